// Round 12
// baseline (265.820 us; speedup 1.0000x reference)
//
#include <hip/hip_runtime.h>
#include <hip/hip_bf16.h>
#include <cstdint>

// B=4, S=2048, D=1024, NH=16, DK=64. Inputs fp32, output fp32.
// Pipeline (4 launches, fast path):
//   convert_all: xb = bf16(x) + 4 weights -> bf16 + rope table (d_out tail)
//   qkv_gemm (3072 blocks, 128x64, BK=64, swizzled, 2-PHASE stage): Q|K
//            stores with fused ROPE; V -> Vt transpose.
//   attn: causal flash, raw-v_exp_f32 softmax, S^T-MFMA. UNTOUCHED.
//   gemm_o: BK=64, swizzled, 2-phase stage, 128x64 tiles -> fp32 out.
//
// R18 post-mortem: rope fusion net +17us (rope2+table+gaps gone; qkv
// 65->77.4 from epilogue cost). qkv now #1: Mfma 29%, VALU 22%, HBM 22% —
// nothing saturated; the m97-style loop exposes the full stage drain
// (glds16 issue -> vmcnt(0) with nothing between).
// R19: 2-phase reorder (T3 minimum): read BOTH kk frags, barrier, issue
// next stage, THEN kk=1 MFMAs -> drain at next-iter barrier is covered by
// 8 MFMAs. Single buffer, LDS 24KiB / 6 blocks/CU preserved. VGPR gate:
// <=85 (512/6) else packing breaks (R12 trap) -> revert. Same for gemm_o.
// Plus: convert4 merged into convert_all (-1 launch).

typedef __attribute__((ext_vector_type(8))) short short8;
typedef __attribute__((ext_vector_type(4))) float float4v;

#define MFMA16(a, b, c) __builtin_amdgcn_mfma_f32_16x16x32_bf16((a), (b), (c), 0, 0, 0)

__device__ __forceinline__ void glds16(const void* g, void* l) {
    __builtin_amdgcn_global_load_lds(
        (const __attribute__((address_space(1))) void*)g,
        (__attribute__((address_space(3))) void*)l, 16, 0, 0);
}

__device__ __forceinline__ unsigned int pk2(float a, float b) {
    __hip_bfloat162 h = __float22bfloat162_rn(make_float2(a, b));  // v_cvt_pk_bf16_f32
    union { __hip_bfloat162 h; unsigned int u; } v; v.h = h;
    return v.u;
}

__device__ __forceinline__ unsigned short f2bf(float x) {
    union { float f; unsigned int u; } v; v.f = x;
    unsigned int r = (v.u + 0x7FFFu + ((v.u >> 16) & 1u)) >> 16;   // RNE
    return (unsigned short)r;
}

__device__ __forceinline__ float bf2f(unsigned short b) {
    union { unsigned int u; float f; } v; v.u = ((unsigned int)b) << 16;
    return v.f;
}

// 8 contiguous fp32 -> bf16 bits (packed converts)
__device__ __forceinline__ short8 load8f(const float* p) {
    const float4 f0 = *(const float4*)p;
    const float4 f1 = *(const float4*)(p + 4);
    union { short8 s; unsigned int u[4]; } r;
    r.u[0] = pk2(f0.x, f0.y);
    r.u[1] = pk2(f0.z, f0.w);
    r.u[2] = pk2(f1.x, f1.y);
    r.u[3] = pk2(f1.z, f1.w);
    return r.s;
}

// ---------------------------------------------------------------------------
// blocks 0..4095: x -> bf16 | 4096..6143: weights -> bf16 (512 each) |
// 6144..6399: rope table (into d_out tail).
__global__ __launch_bounds__(256) void convert_all(
    const float* __restrict__ x, __hip_bfloat16* __restrict__ xb,
    const float* __restrict__ a, const float* __restrict__ b,
    const float* __restrict__ c, const float* __restrict__ d,
    __hip_bfloat16* __restrict__ oa, __hip_bfloat16* __restrict__ ob,
    __hip_bfloat16* __restrict__ oc, __hip_bfloat16* __restrict__ od,
    float2* __restrict__ table)
{
    const int bid = blockIdx.x;
    if (bid < 4096) {
        const int idx = (bid * 256 + threadIdx.x) * 8;
        *(short8*)(xb + idx) = load8f(x + idx);
    } else if (bid < 6144) {
        const int m = (bid - 4096) >> 9;
        const float* in = (m == 0) ? a : (m == 1) ? b : (m == 2) ? c : d;
        __hip_bfloat16* out = (m == 0) ? oa : (m == 1) ? ob : (m == 2) ? oc : od;
        const int idx = (((bid - 4096) & 511) * 256 + threadIdx.x) * 8;
        *(short8*)(out + idx) = load8f(in + idx);
    } else {
        const int idx = (bid - 6144) * 256 + threadIdx.x;   // 65536
        const int pos = idx >> 5, fi = idx & 31;
        const float f = exp2f(-(float)fi * (13.287712379549449f / 32.0f));
        float sn, cs;
        sincosf((float)pos * f, &sn, &cs);
        table[idx] = make_float2(cs, sn);
    }
}

// slow-path (!wbf) converter: x + table only
__global__ __launch_bounds__(256) void convert_x_table(
    const float* __restrict__ in, __hip_bfloat16* __restrict__ out,
    float2* __restrict__ table)
{
    if (blockIdx.x < 4096) {
        const int idx = (blockIdx.x * 256 + threadIdx.x) * 8;
        *(short8*)(out + idx) = load8f(in + idx);
    } else {
        const int idx = (blockIdx.x - 4096) * 256 + threadIdx.x;
        const int pos = idx >> 5, fi = idx & 31;
        const float f = exp2f(-(float)fi * (13.287712379549449f / 32.0f));
        float sn, cs;
        sincosf((float)pos * f, &sn, &cs);
        table[idx] = make_float2(cs, sn);
    }
}

// ---------------------------------------------------------------------------
// Fused QKV GEMM, 128x64 tiles, BK=64, swizzled staging, 2-phase stage
// (BBF=1). Grid 64bm x 48bn. Q/K epilogue applies ROPE from registers.
// V -> swizzled LDS transpose -> Vt[1024][8192]. LDS 24 KiB, acc[4][2].
// ---------------------------------------------------------------------------
template<int BBF>
__global__ __launch_bounds__(256) void qkv_gemm(
    const __hip_bfloat16* __restrict__ Abf,
    const void* __restrict__ Wq, const void* __restrict__ Wk, const void* __restrict__ Wv,
    __hip_bfloat16* __restrict__ Qp, __hip_bfloat16* __restrict__ Kp,
    __hip_bfloat16* __restrict__ Vt, const float2* __restrict__ table)
{
    __shared__ unsigned short smem[12288];   // A[0..8191] | B[8192..12287]; 24 KiB

    const int K = 1024;
    const int bm = blockIdx.x / 48, bn = blockIdx.x % 48;
    const int widx = bn >> 4;              // 0=Q 1=K 2=V
    const int bcol0 = (bn & 15) * 64;
    const void* W = (widx == 0) ? Wq : (widx == 1) ? Wk : Wv;

    const int tid = threadIdx.x;
    const int wave = tid >> 6, lane = tid & 63;
    const int wm = (wave >> 1) * 64, wn = (wave & 1) * 32;
    const int m16 = lane & 15, quad = lane >> 4;

    const int grow = lane >> 3;                              // glds16: 8 rows/instr
    const int gcolsw = ((lane & 7) ^ (lane >> 3)) * 8;       // pre-swizzled col
    const int srow = tid >> 3, scol = (tid & 7) * 8;         // fp32 register-path

    float4v acc[4][2] = {};

    if (BBF) {
        // ---- 2-phase: stage k+1 issued after reads, drained at next barrier
        const __hip_bfloat16* ga = Abf + (int64_t)(bm * 128 + wave * 32 + grow) * K + gcolsw;
        const __hip_bfloat16* gb = (const __hip_bfloat16*)W +
                                   (int64_t)(bcol0 + wave * 16 + grow) * K + gcolsw;
#define QSTG(KOFF)                                                              \
        do {                                                                    \
            glds16(ga + (KOFF),                   &smem[(wave * 32 +  0) * 64]);\
            glds16(ga + (KOFF) + (int64_t)8 * K,  &smem[(wave * 32 +  8) * 64]);\
            glds16(ga + (KOFF) + (int64_t)16 * K, &smem[(wave * 32 + 16) * 64]);\
            glds16(ga + (KOFF) + (int64_t)24 * K, &smem[(wave * 32 + 24) * 64]);\
            glds16(gb + (KOFF),                   &smem[8192 + (wave * 16 + 0) * 64]);\
            glds16(gb + (KOFF) + (int64_t)8 * K,  &smem[8192 + (wave * 16 + 8) * 64]);\
        } while (0)
        QSTG(0);
        for (int k0 = 0; k0 < K; k0 += 64) {
            __syncthreads();                     // stage k0 complete (vmcnt drained)
            short8 af[4], bf[2];
            {   // kk = 0: read + MFMA
                const int ksw = (quad * 8) ^ ((m16 & 7) * 8);
#pragma unroll
                for (int i = 0; i < 4; i++)
                    af[i] = *(const short8*)&smem[(wm + i * 16 + m16) * 64 + ksw];
#pragma unroll
                for (int j = 0; j < 2; j++)
                    bf[j] = *(const short8*)&smem[8192 + (wn + j * 16 + m16) * 64 + ksw];
#pragma unroll
                for (int i = 0; i < 4; i++)
#pragma unroll
                    for (int j = 0; j < 2; j++)
                        acc[i][j] = MFMA16(af[i], bf[j], acc[i][j]);
            }
            {   // kk = 1: read only
                const int ksw = (32 + quad * 8) ^ ((m16 & 7) * 8);
#pragma unroll
                for (int i = 0; i < 4; i++)
                    af[i] = *(const short8*)&smem[(wm + i * 16 + m16) * 64 + ksw];
#pragma unroll
                for (int j = 0; j < 2; j++)
                    bf[j] = *(const short8*)&smem[8192 + (wn + j * 16 + m16) * 64 + ksw];
            }
            __syncthreads();                     // all waves' reads done; LDS free
            if (k0 + 64 < K) QSTG(k0 + 64);      // issue next stage
#pragma unroll
            for (int i = 0; i < 4; i++)          // kk = 1 MFMAs cover the stage
#pragma unroll
                for (int j = 0; j < 2; j++)
                    acc[i][j] = MFMA16(af[i], bf[j], acc[i][j]);
        }
#undef QSTG
    } else {
        // ---- slow path (fp32 weights), original 1-phase structure ----
        for (int k0 = 0; k0 < K; k0 += 64) {
            short8 rb[2];
            const float* Wf = (const float*)W;
#pragma unroll
            for (int t = 0; t < 2; t++)
                rb[t] = load8f(Wf + (int64_t)(bcol0 + t * 32 + srow) * K + k0 + scol);
            __syncthreads();
            {
                const __hip_bfloat16* g = Abf + (int64_t)(bm * 128 + wave * 32 + grow) * K + k0 + gcolsw;
#pragma unroll
                for (int t = 0; t < 4; t++)
                    glds16(g + (int64_t)(t * 8) * K, &smem[(wave * 32 + t * 8) * 64]);
            }
#pragma unroll
            for (int t = 0; t < 2; t++) {
                const int r = t * 32 + srow;
                *(short8*)&smem[8192 + r * 64 + (scol ^ ((r & 7) * 8))] = rb[t];
            }
            __syncthreads();
#pragma unroll
            for (int kk = 0; kk < 2; kk++) {
                const int ksw = (kk * 32 + quad * 8) ^ ((m16 & 7) * 8);
                short8 af[4], bf[2];
#pragma unroll
                for (int i = 0; i < 4; i++)
                    af[i] = *(const short8*)&smem[(wm + i * 16 + m16) * 64 + ksw];
#pragma unroll
                for (int j = 0; j < 2; j++)
                    bf[j] = *(const short8*)&smem[8192 + (wn + j * 16 + m16) * 64 + ksw];
#pragma unroll
                for (int i = 0; i < 4; i++)
#pragma unroll
                    for (int j = 0; j < 2; j++)
                        acc[i][j] = MFMA16(af[i], bf[j], acc[i][j]);
            }
        }
    }

    if (widx == 2) {
        // ---- V: transpose through LDS (XOR swizzle, stride 128); 16 KiB ----
        __syncthreads();
#pragma unroll
        for (int i = 0; i < 4; i++)
#pragma unroll
            for (int j = 0; j < 2; j++) {
                const int col = wn + j * 16 + m16;          // 0..63
                const int key = (col & 7) * 8;
#pragma unroll
                for (int r = 0; r < 4; r++) {
                    const int row = wm + i * 16 + quad * 4 + r;
                    smem[col * 128 + (row ^ key)] = f2bf(acc[i][j][r]);
                }
            }
        __syncthreads();
        const int dc = tid >> 4;          // 0..15
        const int seg = (tid & 15) * 8;   // 0..120 (mult of 8 -> XOR stays contiguous)
#pragma unroll
        for (int pass = 0; pass < 4; pass++) {
            const int dcol = pass * 16 + dc;                // 0..63
            const short8 v = *(const short8*)&smem[dcol * 128 + (seg ^ ((dcol & 7) * 8))];
            *(short8*)((unsigned short*)Vt + (int64_t)(bcol0 + dcol) * 8192 + bm * 128 + seg) = v;
        }
    } else {
        // ---- Q/K: ROPE in registers, then plain store ----
        // C layout: col parity = m16&1 (lane-uniform); partner (col^1) in
        // lane^1 via __shfl_xor. out = v*cos + sgn*vp*sin; Q pre-scaled.
        __hip_bfloat16* dst = (widx == 0) ? Qp : Kp;
        const float scale = (widx == 0) ? 0.18033688011112042f : 1.0f;
        const float sgn = (m16 & 1) ? 1.0f : -1.0f;
        const int row0 = bm * 128 + wm + quad * 4;
        const int col0 = bcol0 + wn + m16;
#pragma unroll
        for (int i = 0; i < 4; i++)
#pragma unroll
            for (int j = 0; j < 2; j++) {
                const int ifq = ((wn + j * 16 + m16) & 63) >> 1;   // pair idx in head
#pragma unroll
                for (int r = 0; r < 4; r++) {
                    const float v = acc[i][j][r] * scale;
                    const float vp = __shfl_xor(v, 1);
                    const int row = row0 + i * 16 + r;
                    const float2 cs = table[(row & 2047) * 32 + ifq];
                    const float out = v * cs.x + sgn * vp * cs.y;
                    dst[(int64_t)row * 1024 + col0 + j * 16] = __float2bfloat16(out);
                }
            }
    }
}

// ---------------------------------------------------------------------------
// Output GEMM, BK=64, 2-phase stage (BBF=1): C[8192][1024] fp32 =
// A(bf16) * B^T. Swizzled staging. BM=128, BN=64 -> 1024 blocks.
// ---------------------------------------------------------------------------
template<int BBF>
__global__ __launch_bounds__(256) void gemm_o(
    const __hip_bfloat16* __restrict__ Abf, const void* __restrict__ B,
    float* __restrict__ C, int M, int N, int K)
{
    __shared__ __hip_bfloat16 lA[128 * 64];   // 16 KiB
    __shared__ __hip_bfloat16 lB[64 * 64];    //  8 KiB

    const int nb = N >> 6;
    const int bm = blockIdx.x / nb, bn = blockIdx.x % nb;
    const int tid = threadIdx.x;
    const int wave = tid >> 6, lane = tid & 63;
    const int wm = (wave >> 1) * 64, wn = (wave & 1) * 32;
    const int m16 = lane & 15, quad = lane >> 4;
    const int grow = lane >> 3;
    const int gcolsw = ((lane & 7) ^ (lane >> 3)) * 8;
    const int srow = tid >> 3, scol = (tid & 7) * 8;

    float4v acc[4][2] = {};

    if (BBF) {
        const __hip_bfloat16* ga = Abf + (int64_t)(bm * 128 + wave * 32 + grow) * K + gcolsw;
        const __hip_bfloat16* gb = (const __hip_bfloat16*)B +
                                   (int64_t)(bn * 64 + wave * 16 + grow) * K + gcolsw;
#define OSTG(KOFF)                                                              \
        do {                                                                    \
            glds16(ga + (KOFF),                   &lA[(wave * 32 +  0) * 64]);  \
            glds16(ga + (KOFF) + (int64_t)8 * K,  &lA[(wave * 32 +  8) * 64]);  \
            glds16(ga + (KOFF) + (int64_t)16 * K, &lA[(wave * 32 + 16) * 64]);  \
            glds16(ga + (KOFF) + (int64_t)24 * K, &lA[(wave * 32 + 24) * 64]);  \
            glds16(gb + (KOFF),                   &lB[(wave * 16 + 0) * 64]);   \
            glds16(gb + (KOFF) + (int64_t)8 * K,  &lB[(wave * 16 + 8) * 64]);   \
        } while (0)
        OSTG(0);
        for (int k0 = 0; k0 < K; k0 += 64) {
            __syncthreads();
            short8 af[4], bf[2];
            {   // kk = 0
                const int ksw = (quad * 8) ^ ((m16 & 7) * 8);
#pragma unroll
                for (int i = 0; i < 4; i++)
                    af[i] = *(const short8*)&lA[(wm + i * 16 + m16) * 64 + ksw];
#pragma unroll
                for (int j = 0; j < 2; j++)
                    bf[j] = *(const short8*)&lB[(wn + j * 16 + m16) * 64 + ksw];
#pragma unroll
                for (int i = 0; i < 4; i++)
#pragma unroll
                    for (int j = 0; j < 2; j++)
                        acc[i][j] = MFMA16(af[i], bf[j], acc[i][j]);
            }
            {   // kk = 1 reads
                const int ksw = (32 + quad * 8) ^ ((m16 & 7) * 8);
#pragma unroll
                for (int i = 0; i < 4; i++)
                    af[i] = *(const short8*)&lA[(wm + i * 16 + m16) * 64 + ksw];
#pragma unroll
                for (int j = 0; j < 2; j++)
                    bf[j] = *(const short8*)&lB[(wn + j * 16 + m16) * 64 + ksw];
            }
            __syncthreads();
            if (k0 + 64 < K) OSTG(k0 + 64);
#pragma unroll
            for (int i = 0; i < 4; i++)
#pragma unroll
                for (int j = 0; j < 2; j++)
                    acc[i][j] = MFMA16(af[i], bf[j], acc[i][j]);
        }
#undef OSTG
    } else {
        for (int k0 = 0; k0 < K; k0 += 64) {
            short8 rb[2];
            const float* Bf = (const float*)B;
#pragma unroll
            for (int t = 0; t < 2; t++)
                rb[t] = load8f(Bf + (int64_t)(bn * 64 + t * 32 + srow) * K + k0 + scol);
            __syncthreads();
            {
                const __hip_bfloat16* g = Abf + (int64_t)(bm * 128 + wave * 32 + grow) * K + k0 + gcolsw;
#pragma unroll
                for (int t = 0; t < 4; t++)
                    glds16(g + (int64_t)(t * 8) * K, &lA[(wave * 32 + t * 8) * 64]);
            }
#pragma unroll
            for (int t = 0; t < 2; t++) {
                const int r = t * 32 + srow;
                *(short8*)&lB[r * 64 + (scol ^ ((r & 7) * 8))] = rb[t];
            }
            __syncthreads();
#pragma unroll
            for (int kk = 0; kk < 2; kk++) {
                const int ksw = (kk * 32 + quad * 8) ^ ((m16 & 7) * 8);
                short8 af[4], bf[2];
#pragma unroll
                for (int i = 0; i < 4; i++)
                    af[i] = *(const short8*)&lA[(wm + i * 16 + m16) * 64 + ksw];
#pragma unroll
                for (int j = 0; j < 2; j++)
                    bf[j] = *(const short8*)&lB[(wn + j * 16 + m16) * 64 + ksw];
#pragma unroll
                for (int i = 0; i < 4; i++)
#pragma unroll
                    for (int j = 0; j < 2; j++)
                        acc[i][j] = MFMA16(af[i], bf[j], acc[i][j]);
            }
        }
    }

    const int row0 = bm * 128 + wm + quad * 4;
    const int col0 = bn * 64 + wn + m16;
#pragma unroll
    for (int i = 0; i < 4; i++)
#pragma unroll
        for (int j = 0; j < 2; j++)
#pragma unroll
            for (int r = 0; r < 4; r++)
                C[(int64_t)(row0 + i * 16 + r) * N + col0 + j * 16] = acc[i][j][r];
}

// ---------------------------------------------------------------------------
// Flash attention, causal, fixed-max softmax (Q pre-scaled by log2e/8;
// p = exp2(score) via RAW v_exp_f32). Block = 4 waves x 32 Q rows = 128;
// Bc = 64. S^T-MFMA: st[mi][ni] = MFMA(K-frag, Q-frag) gives S^T in
// C-layout -> pk2 + ds_write_b64 into lP (XOR swizzle key, r-invariant).
// PV reads lP with the proven 0-conflict b128 pattern. lsum VALU-accumulated
// per (ni, m16); epilogue: 2 shuffles + shfl-gather of 1/l. VGPR 76,
// 5 blocks/CU. UNTOUCHED since R16.
// ---------------------------------------------------------------------------
__global__ __launch_bounds__(256) void attn_kernel(
    const __hip_bfloat16* __restrict__ Q,
    const __hip_bfloat16* __restrict__ Kg,
    const __hip_bfloat16* __restrict__ Vt,
    __hip_bfloat16* __restrict__ O,
    int S, int BS)
{
    // g -> qt permutation: residency groups {x, x+4, x+8, x+12} each sum to
    // 30 kt-units -> per-CU balanced; heavy blocks first. bh stays bid&63 so
    // all qt-blocks of one (b,h) keep sharing an XCD (K/V L2-local).
    const int g = blockIdx.x >> 6;        // 0..15 (S=2048)
    const int qt = (g < 4) ? 15 - g : (g < 8) ? 11 - g : (g < 12) ? g : g - 12;
    const int bh = blockIdx.x & 63;
    const int b = bh >> 4, h = bh & 15;
    const int tid = threadIdx.x;
    const int wave = tid >> 6, lane = tid & 63;
    const int m16 = lane & 15, quad = lane >> 4;

    __shared__ __hip_bfloat16 lK[64 * 64];
    __shared__ __hip_bfloat16 lV[64 * 64];        // Vt tile: [d][kv]
    __shared__ __hip_bfloat16 lP[4][32 * 64];     // total LDS = 32768 B

    const int qrow0 = qt * 128 + wave * 32;
    const int64_t rowbase = (int64_t)b * S;

    // Q frags (B-operand of the S^T MFMA): aq[ni][ks]
    short8 aq[2][2];
#pragma unroll
    for (int i = 0; i < 2; i++) {
        const __hip_bfloat16* qp = Q + (rowbase + qrow0 + i * 16 + m16) * 1024 + h * 64 + quad * 8;
        aq[i][0] = *(const short8*)qp;
        aq[i][1] = *(const short8*)(qp + 32);
    }

    float lsum[2] = {0.f, 0.f};                   // per (ni, lane m16) partials
    float4v o_acc[2][4] = {};

    const int srow = tid >> 3;
    const int scol = (tid & 7) * 8;

    const int ktmax_blk = 2 * qt + 1;
    const int ktmax_w = 2 * qt + (wave >> 1);
    const int k8 = (m16 & 7) * 8;                 // lP swizzle key (elems)

    short8 pk0, pk1, pv0, pv1;
#define PREFETCH(KT)                                                                          \
    do {                                                                                      \
        pk0 = *(const short8*)(Kg + (rowbase + (KT) * 64 + srow) * 1024 + h * 64 + scol);     \
        pk1 = *(const short8*)(Kg + (rowbase + (KT) * 64 + srow + 32) * 1024 + h * 64 + scol);\
        pv0 = *(const short8*)(Vt + (int64_t)(h * 64 + srow) * BS + rowbase + (KT) * 64 + scol);      \
        pv1 = *(const short8*)(Vt + (int64_t)(h * 64 + srow + 32) * BS + rowbase + (KT) * 64 + scol); \
    } while (0)

    PREFETCH(0);

    for (int kt = 0; kt <= ktmax_blk; kt++) {
        __syncthreads();
        *(short8*)&lK[srow * 64 + (scol ^ ((srow & 7) * 8))] = pk0;
        *(short8*)&lK[(srow + 32) * 64 + (scol ^ (((srow + 32) & 7) * 8))] = pk1;
        *(short8*)&lV[srow * 64 + (scol ^ ((srow & 7) * 8))] = pv0;
        *(short8*)&lV[(srow + 32) * 64 + (scol ^ (((srow + 32) & 7) * 8))] = pv1;
        __syncthreads();

        if (kt < ktmax_blk) PREFETCH(kt + 1);

        if (kt <= ktmax_w) {
            // S^T = K Q^T : st[mi][ni], C-layout row = kv, col = qrow
            float4v st[4][2] = {};
#pragma unroll
            for (int mi = 0; mi < 4; mi++) {
                const int n = mi * 16 + m16;
                const int sw = (n & 7) * 8;
                short8 k0 = *(const short8*)&lK[n * 64 + ((quad * 8) ^ sw)];
                short8 k1 = *(const short8*)&lK[n * 64 + ((32 + quad * 8) ^ sw)];
#pragma unroll
                for (int ni = 0; ni < 2; ni++) {
                    st[mi][ni] = MFMA16(k0, aq[ni][0], st[mi][ni]);
                    st[mi][ni] = MFMA16(k1, aq[ni][1], st[mi][ni]);
                }
            }

            // exp2 (raw v_exp_f32), causal mask, lsum, packed b64 write to lP
            const bool need_mask = (kt * 64 + 63 > qrow0);
#pragma unroll
            for (int ni = 0; ni < 2; ni++) {
                const int qg = qrow0 + ni * 16 + m16;
#pragma unroll
                for (int mi = 0; mi < 4; mi++) {
                    float p[4];
#pragma unroll
                    for (int r = 0; r < 4; r++) {
                        p[r] = __builtin_amdgcn_exp2f(st[mi][ni][r]);
                        if (need_mask) {
                            const int kvg = kt * 64 + mi * 16 + quad * 4 + r;
                            if (kvg > qg) p[r] = 0.0f;
                        }
                    }
                    lsum[ni] += (p[0] + p[1]) + (p[2] + p[3]);
                    uint2 w;
                    w.x = pk2(p[0], p[1]);
                    w.y = pk2(p[2], p[3]);
                    *(uint2*)&lP[wave][(ni * 16 + m16) * 64 + ((mi * 16 + quad * 4) ^ k8)] = w;
                }
            }

            // O += P V (lP wave-private; lgkmcnt ordering suffices)
            short8 ap[2][2];
#pragma unroll
            for (int i = 0; i < 2; i++)
#pragma unroll
                for (int ks = 0; ks < 2; ks++)
                    ap[i][ks] = *(const short8*)
                        &lP[wave][(i * 16 + m16) * 64 + ((ks * 32 + quad * 8) ^ k8)];
#pragma unroll
            for (int jd = 0; jd < 4; jd++) {
                const int d = jd * 16 + m16;
                const int sw = (d & 7) * 8;
                short8 b0 = *(const short8*)&lV[d * 64 + ((quad * 8) ^ sw)];
                short8 b1 = *(const short8*)&lV[d * 64 + ((32 + quad * 8) ^ sw)];
#pragma unroll
                for (int i = 0; i < 2; i++) {
                    o_acc[i][jd] = MFMA16(ap[i][0], b0, o_acc[i][jd]);
                    o_acc[i][jd] = MFMA16(ap[i][1], b1, o_acc[i][jd]);
                }
            }
        }
    }
#undef PREFETCH

    // l reduction: after xor16+xor32 every lane holds its m16-column's full
    // sum; invert once, then shfl-gather 1/l for the O-store lanes (no LDS).
    float rinv[2];
#pragma unroll
    for (int ni = 0; ni < 2; ni++) {
        float v = lsum[ni];
        v += __shfl_xor(v, 16);
        v += __shfl_xor(v, 32);
        rinv[ni] = 1.0f / v;
    }
    float ri[2][4];
#pragma unroll
    for (int i = 0; i < 2; i++)
#pragma unroll
        for (int r = 0; r < 4; r++)
            ri[i][r] = __shfl(rinv[i], quad * 4 + r);   // lane p holds column p

#pragma unroll
    for (int i = 0; i < 2; i++)
#pragma unroll
        for (int jd = 0; jd < 4; jd++)
#pragma unroll
            for (int r = 0; r < 4; r++) {
                const int row = qrow0 + i * 16 + quad * 4 + r;
                O[(rowbase + row) * 1024 + h * 64 + jd * 16 + m16] =
                    __float2bfloat16(o_acc[i][jd][r] * ri[i][r]);
            }
}

// ---------------------------------------------------------------------------
extern "C" void kernel_launch(void* const* d_in, const int* in_sizes, int n_in,
                              void* d_out, int out_size, void* d_ws, size_t ws_size,
                              hipStream_t stream)
{
    const float* x  = (const float*)d_in[0];
    const float* qw = (const float*)d_in[1];
    const float* kw = (const float*)d_in[2];
    const float* vw = (const float*)d_in[3];
    const float* ow = (const float*)d_in[4];

    const int BS = 8192, D = 1024, S = 2048;
    const size_t MiB = 1024 * 1024;

    char* ws = (char*)d_ws;
    __hip_bfloat16* xb  = (__hip_bfloat16*)(ws);
    __hip_bfloat16* Qb  = (__hip_bfloat16*)(ws + 16 * MiB); // also AO
    __hip_bfloat16* Kb  = (__hip_bfloat16*)(ws + 32 * MiB);
    __hip_bfloat16* Vtb = (__hip_bfloat16*)(ws + 48 * MiB);
    __hip_bfloat16* wqb = (__hip_bfloat16*)(ws + 64 * MiB);
    __hip_bfloat16* wkb = (__hip_bfloat16*)(ws + 66 * MiB);
    __hip_bfloat16* wvb = (__hip_bfloat16*)(ws + 68 * MiB);
    __hip_bfloat16* wob = (__hip_bfloat16*)(ws + 70 * MiB);
    // rope table lives in d_out's tail (512 KB at +31 MiB): written by the
    // convert launch, read by qkv_gemm, dead before gemm_o overwrites d_out.
    float2* table = (float2*)((char*)d_out + 31 * MiB);
    const bool wbf = ws_size >= 72 * MiB;                   // fast path fits?

    dim3 blk(256);
    if (wbf) {
        convert_all<<<4096 + 2048 + 256, blk, 0, stream>>>(
            x, xb, qw, kw, vw, ow, wqb, wkb, wvb, wob, table);
        qkv_gemm<1><<<64 * 48, blk, 0, stream>>>(xb, wqb, wkb, wvb, Qb, Kb, Vtb, table);
    } else {
        convert_x_table<<<4096 + 256, blk, 0, stream>>>(x, xb, table);
        qkv_gemm<0><<<64 * 48, blk, 0, stream>>>(xb, qw, kw, vw, Qb, Kb, Vtb, table);
    }
    attn_kernel<<<4 * 16 * (S / 128), blk, 0, stream>>>(Qb, Kb, Vtb, Qb /*AO*/, S, BS);
    if (wbf) gemm_o<1><<<(BS / 128) * (D / 64), blk, 0, stream>>>(Qb, wob, (float*)d_out, BS, D, D);
    else     gemm_o<0><<<(BS / 128) * (D / 64), blk, 0, stream>>>(Qb, ow,  (float*)d_out, BS, D, D);
}

// Round 13
// 260.999 us; speedup vs baseline: 1.0185x; 1.0185x over previous
//
#include <hip/hip_runtime.h>
#include <hip/hip_bf16.h>
#include <cstdint>

// B=4, S=2048, D=1024, NH=16, DK=64. Inputs fp32, output fp32.
// Pipeline (4 launches, fast path):
//   convert_all: xb = bf16(x) + 4 weights -> bf16 + rope table (d_out tail)
//   qkv_gemm (3072 blocks, 128x64, BK=64, swizzled, R18 1-phase): Q|K
//            stores with fused ROPE; V -> Vt transpose.
//   attn: causal flash, raw-v_exp_f32 softmax, S^T-MFMA. UNTOUCHED.
//   gemm_o: BK=64, swizzled, R18 1-phase, 128x64 tiles -> fp32 out.
//
// R19 post-mortem: 2-phase stage reorder REGRESSED (qkv 77.4->79.5, VALU
// 22->31.5 from addr recompute; gemm_o worse; total 247.6->265.8). The
// drain was never exposed: at 6 blocks/CU cross-block TLP covers stage
// latency (the m99/m100 lesson — source pipelining adds nothing over
// implicit wave overlap in a 2-barrier loop). Reorder moved the drain
// behind just 8 MFMAs (~10% of HBM latency) instead.
// R20: revert both GEMMs to R18-exact 1-phase; keep ONLY convert_all merge
// (single-variable attribution: if total > 250, the merge is bad too).

typedef __attribute__((ext_vector_type(8))) short short8;
typedef __attribute__((ext_vector_type(4))) float float4v;

#define MFMA16(a, b, c) __builtin_amdgcn_mfma_f32_16x16x32_bf16((a), (b), (c), 0, 0, 0)

__device__ __forceinline__ void glds16(const void* g, void* l) {
    __builtin_amdgcn_global_load_lds(
        (const __attribute__((address_space(1))) void*)g,
        (__attribute__((address_space(3))) void*)l, 16, 0, 0);
}

__device__ __forceinline__ unsigned int pk2(float a, float b) {
    __hip_bfloat162 h = __float22bfloat162_rn(make_float2(a, b));  // v_cvt_pk_bf16_f32
    union { __hip_bfloat162 h; unsigned int u; } v; v.h = h;
    return v.u;
}

__device__ __forceinline__ unsigned short f2bf(float x) {
    union { float f; unsigned int u; } v; v.f = x;
    unsigned int r = (v.u + 0x7FFFu + ((v.u >> 16) & 1u)) >> 16;   // RNE
    return (unsigned short)r;
}

__device__ __forceinline__ float bf2f(unsigned short b) {
    union { unsigned int u; float f; } v; v.u = ((unsigned int)b) << 16;
    return v.f;
}

// 8 contiguous fp32 -> bf16 bits (packed converts)
__device__ __forceinline__ short8 load8f(const float* p) {
    const float4 f0 = *(const float4*)p;
    const float4 f1 = *(const float4*)(p + 4);
    union { short8 s; unsigned int u[4]; } r;
    r.u[0] = pk2(f0.x, f0.y);
    r.u[1] = pk2(f0.z, f0.w);
    r.u[2] = pk2(f1.x, f1.y);
    r.u[3] = pk2(f1.z, f1.w);
    return r.s;
}

// ---------------------------------------------------------------------------
// blocks 0..4095: x -> bf16 | 4096..6143: weights -> bf16 (512 each) |
// 6144..6399: rope table (into d_out tail).
__global__ __launch_bounds__(256) void convert_all(
    const float* __restrict__ x, __hip_bfloat16* __restrict__ xb,
    const float* __restrict__ a, const float* __restrict__ b,
    const float* __restrict__ c, const float* __restrict__ d,
    __hip_bfloat16* __restrict__ oa, __hip_bfloat16* __restrict__ ob,
    __hip_bfloat16* __restrict__ oc, __hip_bfloat16* __restrict__ od,
    float2* __restrict__ table)
{
    const int bid = blockIdx.x;
    if (bid < 4096) {
        const int idx = (bid * 256 + threadIdx.x) * 8;
        *(short8*)(xb + idx) = load8f(x + idx);
    } else if (bid < 6144) {
        const int m = (bid - 4096) >> 9;
        const float* in = (m == 0) ? a : (m == 1) ? b : (m == 2) ? c : d;
        __hip_bfloat16* out = (m == 0) ? oa : (m == 1) ? ob : (m == 2) ? oc : od;
        const int idx = (((bid - 4096) & 511) * 256 + threadIdx.x) * 8;
        *(short8*)(out + idx) = load8f(in + idx);
    } else {
        const int idx = (bid - 6144) * 256 + threadIdx.x;   // 65536
        const int pos = idx >> 5, fi = idx & 31;
        const float f = exp2f(-(float)fi * (13.287712379549449f / 32.0f));
        float sn, cs;
        sincosf((float)pos * f, &sn, &cs);
        table[idx] = make_float2(cs, sn);
    }
}

// slow-path (!wbf) converter: x + table only
__global__ __launch_bounds__(256) void convert_x_table(
    const float* __restrict__ in, __hip_bfloat16* __restrict__ out,
    float2* __restrict__ table)
{
    if (blockIdx.x < 4096) {
        const int idx = (blockIdx.x * 256 + threadIdx.x) * 8;
        *(short8*)(out + idx) = load8f(in + idx);
    } else {
        const int idx = (blockIdx.x - 4096) * 256 + threadIdx.x;
        const int pos = idx >> 5, fi = idx & 31;
        const float f = exp2f(-(float)fi * (13.287712379549449f / 32.0f));
        float sn, cs;
        sincosf((float)pos * f, &sn, &cs);
        table[idx] = make_float2(cs, sn);
    }
}

// ---------------------------------------------------------------------------
// Fused QKV GEMM, 128x64 tiles, BK=64, swizzled staging (R18 1-phase).
// Grid 64bm x 48bn. Q/K epilogue applies ROPE from registers: partner
// col^1 = lane m16^1 via __shfl_xor(v,1); parity m16&1 lane-uniform;
// Q pre-scaled by log2e/8. V -> swizzled LDS transpose -> Vt[1024][8192].
// LDS 24 KiB, acc[4][2], VGPR 76 -> 6 blocks/CU.
// ---------------------------------------------------------------------------
template<int BBF>
__global__ __launch_bounds__(256) void qkv_gemm(
    const __hip_bfloat16* __restrict__ Abf,
    const void* __restrict__ Wq, const void* __restrict__ Wk, const void* __restrict__ Wv,
    __hip_bfloat16* __restrict__ Qp, __hip_bfloat16* __restrict__ Kp,
    __hip_bfloat16* __restrict__ Vt, const float2* __restrict__ table)
{
    __shared__ unsigned short smem[12288];   // A[0..8191] | B[8192..12287]; 24 KiB

    const int K = 1024;
    const int bm = blockIdx.x / 48, bn = blockIdx.x % 48;
    const int widx = bn >> 4;              // 0=Q 1=K 2=V
    const int bcol0 = (bn & 15) * 64;
    const void* W = (widx == 0) ? Wq : (widx == 1) ? Wk : Wv;

    const int tid = threadIdx.x;
    const int wave = tid >> 6, lane = tid & 63;
    const int wm = (wave >> 1) * 64, wn = (wave & 1) * 32;
    const int m16 = lane & 15, quad = lane >> 4;

    const int grow = lane >> 3;                              // glds16: 8 rows/instr
    const int gcolsw = ((lane & 7) ^ (lane >> 3)) * 8;       // pre-swizzled col
    const int srow = tid >> 3, scol = (tid & 7) * 8;         // fp32 register-path

    float4v acc[4][2] = {};

    for (int k0 = 0; k0 < K; k0 += 64) {
        short8 rb[2];
        if (!BBF) {
            const float* Wf = (const float*)W;
#pragma unroll
            for (int t = 0; t < 2; t++)
                rb[t] = load8f(Wf + (int64_t)(bcol0 + t * 32 + srow) * K + k0 + scol);
        }
        __syncthreads();
        {
            const __hip_bfloat16* g = Abf + (int64_t)(bm * 128 + wave * 32 + grow) * K + k0 + gcolsw;
#pragma unroll
            for (int t = 0; t < 4; t++)
                glds16(g + (int64_t)(t * 8) * K, &smem[(wave * 32 + t * 8) * 64]);
        }
        if (BBF) {
            const __hip_bfloat16* g = (const __hip_bfloat16*)W +
                (int64_t)(bcol0 + wave * 16 + grow) * K + k0 + gcolsw;
#pragma unroll
            for (int t = 0; t < 2; t++)
                glds16(g + (int64_t)(t * 8) * K, &smem[8192 + (wave * 16 + t * 8) * 64]);
        } else {
#pragma unroll
            for (int t = 0; t < 2; t++) {
                const int r = t * 32 + srow;
                *(short8*)&smem[8192 + r * 64 + (scol ^ ((r & 7) * 8))] = rb[t];
            }
        }
        __syncthreads();

#pragma unroll
        for (int kk = 0; kk < 2; kk++) {
            const int ksw = (kk * 32 + quad * 8) ^ ((m16 & 7) * 8);
            short8 af[4], bf[2];
#pragma unroll
            for (int i = 0; i < 4; i++)
                af[i] = *(const short8*)&smem[(wm + i * 16 + m16) * 64 + ksw];
#pragma unroll
            for (int j = 0; j < 2; j++)
                bf[j] = *(const short8*)&smem[8192 + (wn + j * 16 + m16) * 64 + ksw];
#pragma unroll
            for (int i = 0; i < 4; i++)
#pragma unroll
                for (int j = 0; j < 2; j++)
                    acc[i][j] = MFMA16(af[i], bf[j], acc[i][j]);
        }
    }

    if (widx == 2) {
        // ---- V: transpose through LDS (XOR swizzle, stride 128); 16 KiB ----
        __syncthreads();
#pragma unroll
        for (int i = 0; i < 4; i++)
#pragma unroll
            for (int j = 0; j < 2; j++) {
                const int col = wn + j * 16 + m16;          // 0..63
                const int key = (col & 7) * 8;
#pragma unroll
                for (int r = 0; r < 4; r++) {
                    const int row = wm + i * 16 + quad * 4 + r;
                    smem[col * 128 + (row ^ key)] = f2bf(acc[i][j][r]);
                }
            }
        __syncthreads();
        const int dc = tid >> 4;          // 0..15
        const int seg = (tid & 15) * 8;   // 0..120 (mult of 8 -> XOR stays contiguous)
#pragma unroll
        for (int pass = 0; pass < 4; pass++) {
            const int dcol = pass * 16 + dc;                // 0..63
            const short8 v = *(const short8*)&smem[dcol * 128 + (seg ^ ((dcol & 7) * 8))];
            *(short8*)((unsigned short*)Vt + (int64_t)(bcol0 + dcol) * 8192 + bm * 128 + seg) = v;
        }
    } else {
        // ---- Q/K: ROPE in registers, then plain store ----
        // C layout: col parity = m16&1 (lane-uniform); partner (col^1) in
        // lane^1 via __shfl_xor. out = v*cos + sgn*vp*sin; Q pre-scaled.
        __hip_bfloat16* dst = (widx == 0) ? Qp : Kp;
        const float scale = (widx == 0) ? 0.18033688011112042f : 1.0f;
        const float sgn = (m16 & 1) ? 1.0f : -1.0f;
        const int row0 = bm * 128 + wm + quad * 4;
        const int col0 = bcol0 + wn + m16;
#pragma unroll
        for (int i = 0; i < 4; i++)
#pragma unroll
            for (int j = 0; j < 2; j++) {
                const int ifq = ((wn + j * 16 + m16) & 63) >> 1;   // pair idx in head
#pragma unroll
                for (int r = 0; r < 4; r++) {
                    const float v = acc[i][j][r] * scale;
                    const float vp = __shfl_xor(v, 1);
                    const int row = row0 + i * 16 + r;
                    const float2 cs = table[(row & 2047) * 32 + ifq];
                    const float out = v * cs.x + sgn * vp * cs.y;
                    dst[(int64_t)row * 1024 + col0 + j * 16] = __float2bfloat16(out);
                }
            }
    }
}

// ---------------------------------------------------------------------------
// Output GEMM, BK=64 (R18 1-phase): C[8192][1024] fp32 = A(bf16) * B^T.
// Swizzled staging. BM=128, BN=64 -> 1024 blocks (exact 4/CU batch).
// ---------------------------------------------------------------------------
template<int BBF>
__global__ __launch_bounds__(256) void gemm_o(
    const __hip_bfloat16* __restrict__ Abf, const void* __restrict__ B,
    float* __restrict__ C, int M, int N, int K)
{
    __shared__ __hip_bfloat16 lA[128 * 64];   // 16 KiB
    __shared__ __hip_bfloat16 lB[64 * 64];    //  8 KiB

    const int nb = N >> 6;
    const int bm = blockIdx.x / nb, bn = blockIdx.x % nb;
    const int tid = threadIdx.x;
    const int wave = tid >> 6, lane = tid & 63;
    const int wm = (wave >> 1) * 64, wn = (wave & 1) * 32;
    const int m16 = lane & 15, quad = lane >> 4;
    const int grow = lane >> 3;
    const int gcolsw = ((lane & 7) ^ (lane >> 3)) * 8;
    const int srow = tid >> 3, scol = (tid & 7) * 8;     // fp32 path: 32 rows x 64 cols

    float4v acc[4][2] = {};

    for (int k0 = 0; k0 < K; k0 += 64) {
        short8 rb[2];
        if (!BBF) {
            const float* Bf = (const float*)B;
#pragma unroll
            for (int t = 0; t < 2; t++)
                rb[t] = load8f(Bf + (int64_t)(bn * 64 + t * 32 + srow) * K + k0 + scol);
        }
        __syncthreads();
        {
            const __hip_bfloat16* g = Abf + (int64_t)(bm * 128 + wave * 32 + grow) * K + k0 + gcolsw;
#pragma unroll
            for (int t = 0; t < 4; t++)
                glds16(g + (int64_t)(t * 8) * K, &lA[(wave * 32 + t * 8) * 64]);
        }
        if (BBF) {
            const __hip_bfloat16* g = (const __hip_bfloat16*)B +
                (int64_t)(bn * 64 + wave * 16 + grow) * K + k0 + gcolsw;
#pragma unroll
            for (int t = 0; t < 2; t++)
                glds16(g + (int64_t)(t * 8) * K, &lB[(wave * 16 + t * 8) * 64]);
        } else {
#pragma unroll
            for (int t = 0; t < 2; t++) {
                const int r = t * 32 + srow;
                *(short8*)&lB[r * 64 + (scol ^ ((r & 7) * 8))] = rb[t];
            }
        }
        __syncthreads();

#pragma unroll
        for (int kk = 0; kk < 2; kk++) {
            const int ksw = (kk * 32 + quad * 8) ^ ((m16 & 7) * 8);
            short8 af[4], bf[2];
#pragma unroll
            for (int i = 0; i < 4; i++)
                af[i] = *(const short8*)&lA[(wm + i * 16 + m16) * 64 + ksw];
#pragma unroll
            for (int j = 0; j < 2; j++)
                bf[j] = *(const short8*)&lB[(wn + j * 16 + m16) * 64 + ksw];
#pragma unroll
            for (int i = 0; i < 4; i++)
#pragma unroll
                for (int j = 0; j < 2; j++)
                    acc[i][j] = MFMA16(af[i], bf[j], acc[i][j]);
        }
    }

    const int row0 = bm * 128 + wm + quad * 4;
    const int col0 = bn * 64 + wn + m16;
#pragma unroll
    for (int i = 0; i < 4; i++)
#pragma unroll
        for (int j = 0; j < 2; j++)
#pragma unroll
            for (int r = 0; r < 4; r++)
                C[(int64_t)(row0 + i * 16 + r) * N + col0 + j * 16] = acc[i][j][r];
}

// ---------------------------------------------------------------------------
// Flash attention, causal, fixed-max softmax (Q pre-scaled by log2e/8;
// p = exp2(score) via RAW v_exp_f32). Block = 4 waves x 32 Q rows = 128;
// Bc = 64. S^T-MFMA: st[mi][ni] = MFMA(K-frag, Q-frag) gives S^T in
// C-layout -> pk2 + ds_write_b64 into lP (XOR swizzle key, r-invariant).
// PV reads lP with the proven 0-conflict b128 pattern. lsum VALU-accumulated
// per (ni, m16); epilogue: 2 shuffles + shfl-gather of 1/l. VGPR 76,
// 5 blocks/CU. UNTOUCHED since R16.
// ---------------------------------------------------------------------------
__global__ __launch_bounds__(256) void attn_kernel(
    const __hip_bfloat16* __restrict__ Q,
    const __hip_bfloat16* __restrict__ Kg,
    const __hip_bfloat16* __restrict__ Vt,
    __hip_bfloat16* __restrict__ O,
    int S, int BS)
{
    // g -> qt permutation: residency groups {x, x+4, x+8, x+12} each sum to
    // 30 kt-units -> per-CU balanced; heavy blocks first. bh stays bid&63 so
    // all qt-blocks of one (b,h) keep sharing an XCD (K/V L2-local).
    const int g = blockIdx.x >> 6;        // 0..15 (S=2048)
    const int qt = (g < 4) ? 15 - g : (g < 8) ? 11 - g : (g < 12) ? g : g - 12;
    const int bh = blockIdx.x & 63;
    const int b = bh >> 4, h = bh & 15;
    const int tid = threadIdx.x;
    const int wave = tid >> 6, lane = tid & 63;
    const int m16 = lane & 15, quad = lane >> 4;

    __shared__ __hip_bfloat16 lK[64 * 64];
    __shared__ __hip_bfloat16 lV[64 * 64];        // Vt tile: [d][kv]
    __shared__ __hip_bfloat16 lP[4][32 * 64];     // total LDS = 32768 B

    const int qrow0 = qt * 128 + wave * 32;
    const int64_t rowbase = (int64_t)b * S;

    // Q frags (B-operand of the S^T MFMA): aq[ni][ks]
    short8 aq[2][2];
#pragma unroll
    for (int i = 0; i < 2; i++) {
        const __hip_bfloat16* qp = Q + (rowbase + qrow0 + i * 16 + m16) * 1024 + h * 64 + quad * 8;
        aq[i][0] = *(const short8*)qp;
        aq[i][1] = *(const short8*)(qp + 32);
    }

    float lsum[2] = {0.f, 0.f};                   // per (ni, lane m16) partials
    float4v o_acc[2][4] = {};

    const int srow = tid >> 3;
    const int scol = (tid & 7) * 8;

    const int ktmax_blk = 2 * qt + 1;
    const int ktmax_w = 2 * qt + (wave >> 1);
    const int k8 = (m16 & 7) * 8;                 // lP swizzle key (elems)

    short8 pk0, pk1, pv0, pv1;
#define PREFETCH(KT)                                                                          \
    do {                                                                                      \
        pk0 = *(const short8*)(Kg + (rowbase + (KT) * 64 + srow) * 1024 + h * 64 + scol);     \
        pk1 = *(const short8*)(Kg + (rowbase + (KT) * 64 + srow + 32) * 1024 + h * 64 + scol);\
        pv0 = *(const short8*)(Vt + (int64_t)(h * 64 + srow) * BS + rowbase + (KT) * 64 + scol);      \
        pv1 = *(const short8*)(Vt + (int64_t)(h * 64 + srow + 32) * BS + rowbase + (KT) * 64 + scol); \
    } while (0)

    PREFETCH(0);

    for (int kt = 0; kt <= ktmax_blk; kt++) {
        __syncthreads();
        *(short8*)&lK[srow * 64 + (scol ^ ((srow & 7) * 8))] = pk0;
        *(short8*)&lK[(srow + 32) * 64 + (scol ^ (((srow + 32) & 7) * 8))] = pk1;
        *(short8*)&lV[srow * 64 + (scol ^ ((srow & 7) * 8))] = pv0;
        *(short8*)&lV[(srow + 32) * 64 + (scol ^ (((srow + 32) & 7) * 8))] = pv1;
        __syncthreads();

        if (kt < ktmax_blk) PREFETCH(kt + 1);

        if (kt <= ktmax_w) {
            // S^T = K Q^T : st[mi][ni], C-layout row = kv, col = qrow
            float4v st[4][2] = {};
#pragma unroll
            for (int mi = 0; mi < 4; mi++) {
                const int n = mi * 16 + m16;
                const int sw = (n & 7) * 8;
                short8 k0 = *(const short8*)&lK[n * 64 + ((quad * 8) ^ sw)];
                short8 k1 = *(const short8*)&lK[n * 64 + ((32 + quad * 8) ^ sw)];
#pragma unroll
                for (int ni = 0; ni < 2; ni++) {
                    st[mi][ni] = MFMA16(k0, aq[ni][0], st[mi][ni]);
                    st[mi][ni] = MFMA16(k1, aq[ni][1], st[mi][ni]);
                }
            }

            // exp2 (raw v_exp_f32), causal mask, lsum, packed b64 write to lP
            const bool need_mask = (kt * 64 + 63 > qrow0);
#pragma unroll
            for (int ni = 0; ni < 2; ni++) {
                const int qg = qrow0 + ni * 16 + m16;
#pragma unroll
                for (int mi = 0; mi < 4; mi++) {
                    float p[4];
#pragma unroll
                    for (int r = 0; r < 4; r++) {
                        p[r] = __builtin_amdgcn_exp2f(st[mi][ni][r]);
                        if (need_mask) {
                            const int kvg = kt * 64 + mi * 16 + quad * 4 + r;
                            if (kvg > qg) p[r] = 0.0f;
                        }
                    }
                    lsum[ni] += (p[0] + p[1]) + (p[2] + p[3]);
                    uint2 w;
                    w.x = pk2(p[0], p[1]);
                    w.y = pk2(p[2], p[3]);
                    *(uint2*)&lP[wave][(ni * 16 + m16) * 64 + ((mi * 16 + quad * 4) ^ k8)] = w;
                }
            }

            // O += P V (lP wave-private; lgkmcnt ordering suffices)
            short8 ap[2][2];
#pragma unroll
            for (int i = 0; i < 2; i++)
#pragma unroll
                for (int ks = 0; ks < 2; ks++)
                    ap[i][ks] = *(const short8*)
                        &lP[wave][(i * 16 + m16) * 64 + ((ks * 32 + quad * 8) ^ k8)];
#pragma unroll
            for (int jd = 0; jd < 4; jd++) {
                const int d = jd * 16 + m16;
                const int sw = (d & 7) * 8;
                short8 b0 = *(const short8*)&lV[d * 64 + ((quad * 8) ^ sw)];
                short8 b1 = *(const short8*)&lV[d * 64 + ((32 + quad * 8) ^ sw)];
#pragma unroll
                for (int i = 0; i < 2; i++) {
                    o_acc[i][jd] = MFMA16(ap[i][0], b0, o_acc[i][jd]);
                    o_acc[i][jd] = MFMA16(ap[i][1], b1, o_acc[i][jd]);
                }
            }
        }
    }
#undef PREFETCH

    // l reduction: after xor16+xor32 every lane holds its m16-column's full
    // sum; invert once, then shfl-gather 1/l for the O-store lanes (no LDS).
    float rinv[2];
#pragma unroll
    for (int ni = 0; ni < 2; ni++) {
        float v = lsum[ni];
        v += __shfl_xor(v, 16);
        v += __shfl_xor(v, 32);
        rinv[ni] = 1.0f / v;
    }
    float ri[2][4];
#pragma unroll
    for (int i = 0; i < 2; i++)
#pragma unroll
        for (int r = 0; r < 4; r++)
            ri[i][r] = __shfl(rinv[i], quad * 4 + r);   // lane p holds column p

#pragma unroll
    for (int i = 0; i < 2; i++)
#pragma unroll
        for (int jd = 0; jd < 4; jd++)
#pragma unroll
            for (int r = 0; r < 4; r++) {
                const int row = qrow0 + i * 16 + quad * 4 + r;
                O[(rowbase + row) * 1024 + h * 64 + jd * 16 + m16] =
                    __float2bfloat16(o_acc[i][jd][r] * ri[i][r]);
            }
}

// ---------------------------------------------------------------------------
extern "C" void kernel_launch(void* const* d_in, const int* in_sizes, int n_in,
                              void* d_out, int out_size, void* d_ws, size_t ws_size,
                              hipStream_t stream)
{
    const float* x  = (const float*)d_in[0];
    const float* qw = (const float*)d_in[1];
    const float* kw = (const float*)d_in[2];
    const float* vw = (const float*)d_in[3];
    const float* ow = (const float*)d_in[4];

    const int BS = 8192, D = 1024, S = 2048;
    const size_t MiB = 1024 * 1024;

    char* ws = (char*)d_ws;
    __hip_bfloat16* xb  = (__hip_bfloat16*)(ws);
    __hip_bfloat16* Qb  = (__hip_bfloat16*)(ws + 16 * MiB); // also AO
    __hip_bfloat16* Kb  = (__hip_bfloat16*)(ws + 32 * MiB);
    __hip_bfloat16* Vtb = (__hip_bfloat16*)(ws + 48 * MiB);
    __hip_bfloat16* wqb = (__hip_bfloat16*)(ws + 64 * MiB);
    __hip_bfloat16* wkb = (__hip_bfloat16*)(ws + 66 * MiB);
    __hip_bfloat16* wvb = (__hip_bfloat16*)(ws + 68 * MiB);
    __hip_bfloat16* wob = (__hip_bfloat16*)(ws + 70 * MiB);
    // rope table lives in d_out's tail (512 KB at +31 MiB): written by the
    // convert launch, read by qkv_gemm, dead before gemm_o overwrites d_out.
    float2* table = (float2*)((char*)d_out + 31 * MiB);
    const bool wbf = ws_size >= 72 * MiB;                   // fast path fits?

    dim3 blk(256);
    if (wbf) {
        convert_all<<<4096 + 2048 + 256, blk, 0, stream>>>(
            x, xb, qw, kw, vw, ow, wqb, wkb, wvb, wob, table);
        qkv_gemm<1><<<64 * 48, blk, 0, stream>>>(xb, wqb, wkb, wvb, Qb, Kb, Vtb, table);
    } else {
        convert_x_table<<<4096 + 256, blk, 0, stream>>>(x, xb, table);
        qkv_gemm<0><<<64 * 48, blk, 0, stream>>>(xb, qw, kw, vw, Qb, Kb, Vtb, table);
    }
    attn_kernel<<<4 * 16 * (S / 128), blk, 0, stream>>>(Qb, Kb, Vtb, Qb /*AO*/, S, BS);
    if (wbf) gemm_o<1><<<(BS / 128) * (D / 64), blk, 0, stream>>>(Qb, wob, (float*)d_out, BS, D, D);
    else     gemm_o<0><<<(BS / 128) * (D / 64), blk, 0, stream>>>(Qb, ow,  (float*)d_out, BS, D, D);
}

// Round 14
// 253.557 us; speedup vs baseline: 1.0484x; 1.0293x over previous
//
#include <hip/hip_runtime.h>
#include <hip/hip_bf16.h>
#include <cstdint>

// B=4, S=2048, D=1024, NH=16, DK=64. Inputs fp32, output fp32.
// Pipeline (5 launches):
//   convert_x_table: xb = bf16(x) + rope cos/sin table (into d_out tail)
//   convert4: weights -> bf16 (fast path)
//   qkv_gemm (3072 blocks, 128x64, BK=64, swizzled): Q|K stores WITH ROPE
//            fused in epilogue (shfl_xor(1) pair exchange); V -> Vt transpose.
//   attn: causal flash, raw-v_exp_f32 softmax, S^T-MFMA. UNTOUCHED.
//   gemm_o: BK=64, swizzled, 128x64 tiles -> fp32 out.
//
// R20 post-mortem: GEMM revert confirmed (qkv 76.5, VGPR 76) but total
// 261 vs R18's 247.6 — ledger isolates the convert_all merge (+13.4us:
// R19-R20 = 4.8 = 2-phase cost, so the rest is the merge or container
// noise). Per R20's pre-commitment: revert to R18-exact 5-launch split.
// R21 = R18 byte-identical. If ~248 -> merge was bad (stays dead);
// if ~260 -> R18 was a fast container and configs are equivalent.

typedef __attribute__((ext_vector_type(8))) short short8;
typedef __attribute__((ext_vector_type(4))) float float4v;

#define MFMA16(a, b, c) __builtin_amdgcn_mfma_f32_16x16x32_bf16((a), (b), (c), 0, 0, 0)

__device__ __forceinline__ void glds16(const void* g, void* l) {
    __builtin_amdgcn_global_load_lds(
        (const __attribute__((address_space(1))) void*)g,
        (__attribute__((address_space(3))) void*)l, 16, 0, 0);
}

__device__ __forceinline__ unsigned int pk2(float a, float b) {
    __hip_bfloat162 h = __float22bfloat162_rn(make_float2(a, b));  // v_cvt_pk_bf16_f32
    union { __hip_bfloat162 h; unsigned int u; } v; v.h = h;
    return v.u;
}

__device__ __forceinline__ unsigned short f2bf(float x) {
    union { float f; unsigned int u; } v; v.f = x;
    unsigned int r = (v.u + 0x7FFFu + ((v.u >> 16) & 1u)) >> 16;   // RNE
    return (unsigned short)r;
}

__device__ __forceinline__ float bf2f(unsigned short b) {
    union { unsigned int u; float f; } v; v.u = ((unsigned int)b) << 16;
    return v.f;
}

// 8 contiguous fp32 -> bf16 bits (packed converts)
__device__ __forceinline__ short8 load8f(const float* p) {
    const float4 f0 = *(const float4*)p;
    const float4 f1 = *(const float4*)(p + 4);
    union { short8 s; unsigned int u[4]; } r;
    r.u[0] = pk2(f0.x, f0.y);
    r.u[1] = pk2(f0.z, f0.w);
    r.u[2] = pk2(f1.x, f1.y);
    r.u[3] = pk2(f1.z, f1.w);
    return r.s;
}

// ---------------------------------------------------------------------------
// x -> bf16 (blocks 0..4095) + rope table (blocks 4096..4351, into d_out tail)
__global__ __launch_bounds__(256) void convert_x_table(
    const float* __restrict__ in, __hip_bfloat16* __restrict__ out,
    float2* __restrict__ table)
{
    if (blockIdx.x < 4096) {
        const int idx = (blockIdx.x * 256 + threadIdx.x) * 8;
        *(short8*)(out + idx) = load8f(in + idx);
    } else {
        const int idx = (blockIdx.x - 4096) * 256 + threadIdx.x;   // 65536
        const int pos = idx >> 5, fi = idx & 31;
        const float f = exp2f(-(float)fi * (13.287712379549449f / 32.0f));
        float sn, cs;
        sincosf((float)pos * f, &sn, &cs);
        table[idx] = make_float2(cs, sn);
    }
}

// 4 weight matrices (1M elems each) in one launch: 512 blocks per matrix.
__global__ __launch_bounds__(256) void convert4_kernel(
    const float* __restrict__ a, const float* __restrict__ b,
    const float* __restrict__ c, const float* __restrict__ d,
    __hip_bfloat16* __restrict__ oa, __hip_bfloat16* __restrict__ ob,
    __hip_bfloat16* __restrict__ oc, __hip_bfloat16* __restrict__ od)
{
    const int m = blockIdx.x >> 9;
    const float* in = (m == 0) ? a : (m == 1) ? b : (m == 2) ? c : d;
    __hip_bfloat16* out = (m == 0) ? oa : (m == 1) ? ob : (m == 2) ? oc : od;
    const int idx = ((blockIdx.x & 511) * 256 + threadIdx.x) * 8;
    *(short8*)(out + idx) = load8f(in + idx);
}

// ---------------------------------------------------------------------------
// Fused QKV GEMM, 128x64 tiles, BK=64, swizzled staging. Grid 64bm x 48bn.
// Q/K epilogue applies ROPE from registers: partner col^1 = lane m16^1 via
// __shfl_xor(v,1); parity m16&1 lane-uniform; Q pre-scaled by log2e/8.
// V -> swizzled LDS transpose -> Vt[1024][8192]. LDS 24 KiB, acc[4][2].
// ---------------------------------------------------------------------------
template<int BBF>
__global__ __launch_bounds__(256) void qkv_gemm(
    const __hip_bfloat16* __restrict__ Abf,
    const void* __restrict__ Wq, const void* __restrict__ Wk, const void* __restrict__ Wv,
    __hip_bfloat16* __restrict__ Qp, __hip_bfloat16* __restrict__ Kp,
    __hip_bfloat16* __restrict__ Vt, const float2* __restrict__ table)
{
    __shared__ unsigned short smem[12288];   // A[0..8191] | B[8192..12287]; 24 KiB

    const int K = 1024;
    const int bm = blockIdx.x / 48, bn = blockIdx.x % 48;
    const int widx = bn >> 4;              // 0=Q 1=K 2=V
    const int bcol0 = (bn & 15) * 64;
    const void* W = (widx == 0) ? Wq : (widx == 1) ? Wk : Wv;

    const int tid = threadIdx.x;
    const int wave = tid >> 6, lane = tid & 63;
    const int wm = (wave >> 1) * 64, wn = (wave & 1) * 32;
    const int m16 = lane & 15, quad = lane >> 4;

    const int grow = lane >> 3;                              // glds16: 8 rows/instr
    const int gcolsw = ((lane & 7) ^ (lane >> 3)) * 8;       // pre-swizzled col
    const int srow = tid >> 3, scol = (tid & 7) * 8;         // fp32 register-path

    float4v acc[4][2] = {};

    for (int k0 = 0; k0 < K; k0 += 64) {
        short8 rb[2];
        if (!BBF) {
            const float* Wf = (const float*)W;
#pragma unroll
            for (int t = 0; t < 2; t++)
                rb[t] = load8f(Wf + (int64_t)(bcol0 + t * 32 + srow) * K + k0 + scol);
        }
        __syncthreads();
        {
            const __hip_bfloat16* g = Abf + (int64_t)(bm * 128 + wave * 32 + grow) * K + k0 + gcolsw;
#pragma unroll
            for (int t = 0; t < 4; t++)
                glds16(g + (int64_t)(t * 8) * K, &smem[(wave * 32 + t * 8) * 64]);
        }
        if (BBF) {
            const __hip_bfloat16* g = (const __hip_bfloat16*)W +
                (int64_t)(bcol0 + wave * 16 + grow) * K + k0 + gcolsw;
#pragma unroll
            for (int t = 0; t < 2; t++)
                glds16(g + (int64_t)(t * 8) * K, &smem[8192 + (wave * 16 + t * 8) * 64]);
        } else {
#pragma unroll
            for (int t = 0; t < 2; t++) {
                const int r = t * 32 + srow;
                *(short8*)&smem[8192 + r * 64 + (scol ^ ((r & 7) * 8))] = rb[t];
            }
        }
        __syncthreads();

#pragma unroll
        for (int kk = 0; kk < 2; kk++) {
            const int ksw = (kk * 32 + quad * 8) ^ ((m16 & 7) * 8);
            short8 af[4], bf[2];
#pragma unroll
            for (int i = 0; i < 4; i++)
                af[i] = *(const short8*)&smem[(wm + i * 16 + m16) * 64 + ksw];
#pragma unroll
            for (int j = 0; j < 2; j++)
                bf[j] = *(const short8*)&smem[8192 + (wn + j * 16 + m16) * 64 + ksw];
#pragma unroll
            for (int i = 0; i < 4; i++)
#pragma unroll
                for (int j = 0; j < 2; j++)
                    acc[i][j] = MFMA16(af[i], bf[j], acc[i][j]);
        }
    }

    if (widx == 2) {
        // ---- V: transpose through LDS (XOR swizzle, stride 128); 16 KiB ----
        __syncthreads();
#pragma unroll
        for (int i = 0; i < 4; i++)
#pragma unroll
            for (int j = 0; j < 2; j++) {
                const int col = wn + j * 16 + m16;          // 0..63
                const int key = (col & 7) * 8;
#pragma unroll
                for (int r = 0; r < 4; r++) {
                    const int row = wm + i * 16 + quad * 4 + r;
                    smem[col * 128 + (row ^ key)] = f2bf(acc[i][j][r]);
                }
            }
        __syncthreads();
        const int dc = tid >> 4;          // 0..15
        const int seg = (tid & 15) * 8;   // 0..120 (mult of 8 -> XOR stays contiguous)
#pragma unroll
        for (int pass = 0; pass < 4; pass++) {
            const int dcol = pass * 16 + dc;                // 0..63
            const short8 v = *(const short8*)&smem[dcol * 128 + (seg ^ ((dcol & 7) * 8))];
            *(short8*)((unsigned short*)Vt + (int64_t)(bcol0 + dcol) * 8192 + bm * 128 + seg) = v;
        }
    } else {
        // ---- Q/K: ROPE in registers, then plain store ----
        // C layout: col parity = m16&1 (lane-uniform); partner (col^1) in
        // lane^1 via __shfl_xor. out = v*cos + sgn*vp*sin; Q pre-scaled.
        __hip_bfloat16* dst = (widx == 0) ? Qp : Kp;
        const float scale = (widx == 0) ? 0.18033688011112042f : 1.0f;
        const float sgn = (m16 & 1) ? 1.0f : -1.0f;
        const int row0 = bm * 128 + wm + quad * 4;
        const int col0 = bcol0 + wn + m16;
#pragma unroll
        for (int i = 0; i < 4; i++)
#pragma unroll
            for (int j = 0; j < 2; j++) {
                const int ifq = ((wn + j * 16 + m16) & 63) >> 1;   // pair idx in head
#pragma unroll
                for (int r = 0; r < 4; r++) {
                    const float v = acc[i][j][r] * scale;
                    const float vp = __shfl_xor(v, 1);
                    const int row = row0 + i * 16 + r;
                    const float2 cs = table[(row & 2047) * 32 + ifq];
                    const float out = v * cs.x + sgn * vp * cs.y;
                    dst[(int64_t)row * 1024 + col0 + j * 16] = __float2bfloat16(out);
                }
            }
    }
}

// ---------------------------------------------------------------------------
// Output GEMM, BK=64: C[8192][1024] fp32 = A(bf16, glds16) * B^T.
// Swizzled staging. BM=128, BN=64 -> 1024 blocks (exact 4/CU batch).
// ---------------------------------------------------------------------------
template<int BBF>
__global__ __launch_bounds__(256) void gemm_o(
    const __hip_bfloat16* __restrict__ Abf, const void* __restrict__ B,
    float* __restrict__ C, int M, int N, int K)
{
    __shared__ __hip_bfloat16 lA[128 * 64];   // 16 KiB
    __shared__ __hip_bfloat16 lB[64 * 64];    //  8 KiB

    const int nb = N >> 6;
    const int bm = blockIdx.x / nb, bn = blockIdx.x % nb;
    const int tid = threadIdx.x;
    const int wave = tid >> 6, lane = tid & 63;
    const int wm = (wave >> 1) * 64, wn = (wave & 1) * 32;
    const int m16 = lane & 15, quad = lane >> 4;
    const int grow = lane >> 3;
    const int gcolsw = ((lane & 7) ^ (lane >> 3)) * 8;
    const int srow = tid >> 3, scol = (tid & 7) * 8;     // fp32 path: 32 rows x 64 cols

    float4v acc[4][2] = {};

    for (int k0 = 0; k0 < K; k0 += 64) {
        short8 rb[2];
        if (!BBF) {
            const float* Bf = (const float*)B;
#pragma unroll
            for (int t = 0; t < 2; t++)
                rb[t] = load8f(Bf + (int64_t)(bn * 64 + t * 32 + srow) * K + k0 + scol);
        }
        __syncthreads();
        {
            const __hip_bfloat16* g = Abf + (int64_t)(bm * 128 + wave * 32 + grow) * K + k0 + gcolsw;
#pragma unroll
            for (int t = 0; t < 4; t++)
                glds16(g + (int64_t)(t * 8) * K, &lA[(wave * 32 + t * 8) * 64]);
        }
        if (BBF) {
            const __hip_bfloat16* g = (const __hip_bfloat16*)B +
                (int64_t)(bn * 64 + wave * 16 + grow) * K + k0 + gcolsw;
#pragma unroll
            for (int t = 0; t < 2; t++)
                glds16(g + (int64_t)(t * 8) * K, &lB[(wave * 16 + t * 8) * 64]);
        } else {
#pragma unroll
            for (int t = 0; t < 2; t++) {
                const int r = t * 32 + srow;
                *(short8*)&lB[r * 64 + (scol ^ ((r & 7) * 8))] = rb[t];
            }
        }
        __syncthreads();

#pragma unroll
        for (int kk = 0; kk < 2; kk++) {
            const int ksw = (kk * 32 + quad * 8) ^ ((m16 & 7) * 8);
            short8 af[4], bf[2];
#pragma unroll
            for (int i = 0; i < 4; i++)
                af[i] = *(const short8*)&lA[(wm + i * 16 + m16) * 64 + ksw];
#pragma unroll
            for (int j = 0; j < 2; j++)
                bf[j] = *(const short8*)&lB[(wn + j * 16 + m16) * 64 + ksw];
#pragma unroll
            for (int i = 0; i < 4; i++)
#pragma unroll
                for (int j = 0; j < 2; j++)
                    acc[i][j] = MFMA16(af[i], bf[j], acc[i][j]);
        }
    }

    const int row0 = bm * 128 + wm + quad * 4;
    const int col0 = bn * 64 + wn + m16;
#pragma unroll
    for (int i = 0; i < 4; i++)
#pragma unroll
        for (int j = 0; j < 2; j++)
#pragma unroll
            for (int r = 0; r < 4; r++)
                C[(int64_t)(row0 + i * 16 + r) * N + col0 + j * 16] = acc[i][j][r];
}

// ---------------------------------------------------------------------------
// Flash attention, causal, fixed-max softmax (Q pre-scaled by log2e/8;
// p = exp2(score) via RAW v_exp_f32). Block = 4 waves x 32 Q rows = 128;
// Bc = 64. S^T-MFMA: st[mi][ni] = MFMA(K-frag, Q-frag) gives S^T in
// C-layout -> pk2 + ds_write_b64 into lP (XOR swizzle key, r-invariant).
// PV reads lP with the proven 0-conflict b128 pattern. lsum VALU-accumulated
// per (ni, m16); epilogue: 2 shuffles + shfl-gather of 1/l. VGPR 76,
// 5 blocks/CU. UNTOUCHED since R16.
// ---------------------------------------------------------------------------
__global__ __launch_bounds__(256) void attn_kernel(
    const __hip_bfloat16* __restrict__ Q,
    const __hip_bfloat16* __restrict__ Kg,
    const __hip_bfloat16* __restrict__ Vt,
    __hip_bfloat16* __restrict__ O,
    int S, int BS)
{
    // g -> qt permutation: residency groups {x, x+4, x+8, x+12} each sum to
    // 30 kt-units -> per-CU balanced; heavy blocks first. bh stays bid&63 so
    // all qt-blocks of one (b,h) keep sharing an XCD (K/V L2-local).
    const int g = blockIdx.x >> 6;        // 0..15 (S=2048)
    const int qt = (g < 4) ? 15 - g : (g < 8) ? 11 - g : (g < 12) ? g : g - 12;
    const int bh = blockIdx.x & 63;
    const int b = bh >> 4, h = bh & 15;
    const int tid = threadIdx.x;
    const int wave = tid >> 6, lane = tid & 63;
    const int m16 = lane & 15, quad = lane >> 4;

    __shared__ __hip_bfloat16 lK[64 * 64];
    __shared__ __hip_bfloat16 lV[64 * 64];        // Vt tile: [d][kv]
    __shared__ __hip_bfloat16 lP[4][32 * 64];     // total LDS = 32768 B

    const int qrow0 = qt * 128 + wave * 32;
    const int64_t rowbase = (int64_t)b * S;

    // Q frags (B-operand of the S^T MFMA): aq[ni][ks]
    short8 aq[2][2];
#pragma unroll
    for (int i = 0; i < 2; i++) {
        const __hip_bfloat16* qp = Q + (rowbase + qrow0 + i * 16 + m16) * 1024 + h * 64 + quad * 8;
        aq[i][0] = *(const short8*)qp;
        aq[i][1] = *(const short8*)(qp + 32);
    }

    float lsum[2] = {0.f, 0.f};                   // per (ni, lane m16) partials
    float4v o_acc[2][4] = {};

    const int srow = tid >> 3;
    const int scol = (tid & 7) * 8;

    const int ktmax_blk = 2 * qt + 1;
    const int ktmax_w = 2 * qt + (wave >> 1);
    const int k8 = (m16 & 7) * 8;                 // lP swizzle key (elems)

    short8 pk0, pk1, pv0, pv1;
#define PREFETCH(KT)                                                                          \
    do {                                                                                      \
        pk0 = *(const short8*)(Kg + (rowbase + (KT) * 64 + srow) * 1024 + h * 64 + scol);     \
        pk1 = *(const short8*)(Kg + (rowbase + (KT) * 64 + srow + 32) * 1024 + h * 64 + scol);\
        pv0 = *(const short8*)(Vt + (int64_t)(h * 64 + srow) * BS + rowbase + (KT) * 64 + scol);      \
        pv1 = *(const short8*)(Vt + (int64_t)(h * 64 + srow + 32) * BS + rowbase + (KT) * 64 + scol); \
    } while (0)

    PREFETCH(0);

    for (int kt = 0; kt <= ktmax_blk; kt++) {
        __syncthreads();
        *(short8*)&lK[srow * 64 + (scol ^ ((srow & 7) * 8))] = pk0;
        *(short8*)&lK[(srow + 32) * 64 + (scol ^ (((srow + 32) & 7) * 8))] = pk1;
        *(short8*)&lV[srow * 64 + (scol ^ ((srow & 7) * 8))] = pv0;
        *(short8*)&lV[(srow + 32) * 64 + (scol ^ (((srow + 32) & 7) * 8))] = pv1;
        __syncthreads();

        if (kt < ktmax_blk) PREFETCH(kt + 1);

        if (kt <= ktmax_w) {
            // S^T = K Q^T : st[mi][ni], C-layout row = kv, col = qrow
            float4v st[4][2] = {};
#pragma unroll
            for (int mi = 0; mi < 4; mi++) {
                const int n = mi * 16 + m16;
                const int sw = (n & 7) * 8;
                short8 k0 = *(const short8*)&lK[n * 64 + ((quad * 8) ^ sw)];
                short8 k1 = *(const short8*)&lK[n * 64 + ((32 + quad * 8) ^ sw)];
#pragma unroll
                for (int ni = 0; ni < 2; ni++) {
                    st[mi][ni] = MFMA16(k0, aq[ni][0], st[mi][ni]);
                    st[mi][ni] = MFMA16(k1, aq[ni][1], st[mi][ni]);
                }
            }

            // exp2 (raw v_exp_f32), causal mask, lsum, packed b64 write to lP
            const bool need_mask = (kt * 64 + 63 > qrow0);
#pragma unroll
            for (int ni = 0; ni < 2; ni++) {
                const int qg = qrow0 + ni * 16 + m16;
#pragma unroll
                for (int mi = 0; mi < 4; mi++) {
                    float p[4];
#pragma unroll
                    for (int r = 0; r < 4; r++) {
                        p[r] = __builtin_amdgcn_exp2f(st[mi][ni][r]);
                        if (need_mask) {
                            const int kvg = kt * 64 + mi * 16 + quad * 4 + r;
                            if (kvg > qg) p[r] = 0.0f;
                        }
                    }
                    lsum[ni] += (p[0] + p[1]) + (p[2] + p[3]);
                    uint2 w;
                    w.x = pk2(p[0], p[1]);
                    w.y = pk2(p[2], p[3]);
                    *(uint2*)&lP[wave][(ni * 16 + m16) * 64 + ((mi * 16 + quad * 4) ^ k8)] = w;
                }
            }

            // O += P V (lP wave-private; lgkmcnt ordering suffices)
            short8 ap[2][2];
#pragma unroll
            for (int i = 0; i < 2; i++)
#pragma unroll
                for (int ks = 0; ks < 2; ks++)
                    ap[i][ks] = *(const short8*)
                        &lP[wave][(i * 16 + m16) * 64 + ((ks * 32 + quad * 8) ^ k8)];
#pragma unroll
            for (int jd = 0; jd < 4; jd++) {
                const int d = jd * 16 + m16;
                const int sw = (d & 7) * 8;
                short8 b0 = *(const short8*)&lV[d * 64 + ((quad * 8) ^ sw)];
                short8 b1 = *(const short8*)&lV[d * 64 + ((32 + quad * 8) ^ sw)];
#pragma unroll
                for (int i = 0; i < 2; i++) {
                    o_acc[i][jd] = MFMA16(ap[i][0], b0, o_acc[i][jd]);
                    o_acc[i][jd] = MFMA16(ap[i][1], b1, o_acc[i][jd]);
                }
            }
        }
    }
#undef PREFETCH

    // l reduction: after xor16+xor32 every lane holds its m16-column's full
    // sum; invert once, then shfl-gather 1/l for the O-store lanes (no LDS).
    float rinv[2];
#pragma unroll
    for (int ni = 0; ni < 2; ni++) {
        float v = lsum[ni];
        v += __shfl_xor(v, 16);
        v += __shfl_xor(v, 32);
        rinv[ni] = 1.0f / v;
    }
    float ri[2][4];
#pragma unroll
    for (int i = 0; i < 2; i++)
#pragma unroll
        for (int r = 0; r < 4; r++)
            ri[i][r] = __shfl(rinv[i], quad * 4 + r);   // lane p holds column p

#pragma unroll
    for (int i = 0; i < 2; i++)
#pragma unroll
        for (int jd = 0; jd < 4; jd++)
#pragma unroll
            for (int r = 0; r < 4; r++) {
                const int row = qrow0 + i * 16 + quad * 4 + r;
                O[(rowbase + row) * 1024 + h * 64 + jd * 16 + m16] =
                    __float2bfloat16(o_acc[i][jd][r] * ri[i][r]);
            }
}

// ---------------------------------------------------------------------------
extern "C" void kernel_launch(void* const* d_in, const int* in_sizes, int n_in,
                              void* d_out, int out_size, void* d_ws, size_t ws_size,
                              hipStream_t stream)
{
    const float* x  = (const float*)d_in[0];
    const float* qw = (const float*)d_in[1];
    const float* kw = (const float*)d_in[2];
    const float* vw = (const float*)d_in[3];
    const float* ow = (const float*)d_in[4];

    const int BS = 8192, D = 1024, S = 2048;
    const size_t MiB = 1024 * 1024;

    char* ws = (char*)d_ws;
    __hip_bfloat16* xb  = (__hip_bfloat16*)(ws);
    __hip_bfloat16* Qb  = (__hip_bfloat16*)(ws + 16 * MiB); // also AO
    __hip_bfloat16* Kb  = (__hip_bfloat16*)(ws + 32 * MiB);
    __hip_bfloat16* Vtb = (__hip_bfloat16*)(ws + 48 * MiB);
    __hip_bfloat16* wqb = (__hip_bfloat16*)(ws + 64 * MiB);
    __hip_bfloat16* wkb = (__hip_bfloat16*)(ws + 66 * MiB);
    __hip_bfloat16* wvb = (__hip_bfloat16*)(ws + 68 * MiB);
    __hip_bfloat16* wob = (__hip_bfloat16*)(ws + 70 * MiB);
    // rope table lives in d_out's tail (512 KB at +31 MiB): written by
    // convert_x_table, read by qkv_gemm, dead before gemm_o overwrites d_out.
    float2* table = (float2*)((char*)d_out + 31 * MiB);
    const bool wbf = ws_size >= 72 * MiB;                   // fast path fits?

    dim3 blk(256);
    convert_x_table<<<4096 + 256, blk, 0, stream>>>(x, xb, table);
    if (wbf) {
        convert4_kernel<<<4 * (D * D) / 2048, blk, 0, stream>>>(
            qw, kw, vw, ow, wqb, wkb, wvb, wob);
        qkv_gemm<1><<<64 * 48, blk, 0, stream>>>(xb, wqb, wkb, wvb, Qb, Kb, Vtb, table);
    } else {
        qkv_gemm<0><<<64 * 48, blk, 0, stream>>>(xb, qw, kw, vw, Qb, Kb, Vtb, table);
    }
    attn_kernel<<<4 * 16 * (S / 128), blk, 0, stream>>>(Qb, Kb, Vtb, Qb /*AO*/, S, BS);
    if (wbf) gemm_o<1><<<(BS / 128) * (D / 64), blk, 0, stream>>>(Qb, wob, (float*)d_out, BS, D, D);
    else     gemm_o<0><<<(BS / 128) * (D / 64), blk, 0, stream>>>(Qb, ow,  (float*)d_out, BS, D, D);
}

// Round 16
// 250.521 us; speedup vs baseline: 1.0611x; 1.0121x over previous
//
#include <hip/hip_runtime.h>
#include <hip/hip_bf16.h>
#include <cstdint>

// B=4, S=2048, D=1024, NH=16, DK=64. Inputs fp32, output fp32.
// Pipeline (5 launches):
//   convert_x_table: xb = bf16(x) + rope cos/sin table (into d_out tail)
//   convert4: weights -> bf16 (fast path)
//   qkv_gemm (3072 blocks, 128x64, BK=64, swizzled staging, XCD-reuse
//            remap): Q|K stores with fused ROPE; V -> Vt transpose.
//   attn: causal flash, raw-v_exp_f32 softmax, S^T-MFMA. UNTOUCHED.
//   gemm_o: BK=64, swizzled, XCD-reuse remap, 128x64 tiles -> fp32 out.
//
// R22 (resubmit; R22 bench failed on container acquisition): qkv shows
// nothing saturated (Mfma 26/VALU 20/HBM 21) yet 81us. Cache arithmetic:
// A-tiles re-read by 48 bn-blocks spread round-robin over 8 XCDs ->
// L3->L2 traffic ~1.15GB/81us = 14 TB/s (likely Infinity-Cache ceiling;
// invisible in FETCH_SIZE per the L3-masking gotcha). Fix: XCD-reuse
// blockIdx remap (bijective): xcd=bid&7, j=bid>>3; bm=xcd+8*(j&7);
// bn=j>>3 — all 48 sharers of an A-tile on ONE XCD, 8 consecutive blocks
// share a B-tile in L2. Pred L3 traffic -> ~70MB. Same for gemm_o.
// If flat -> qkv is latency-bound; pipeline at practical structural limit.

typedef __attribute__((ext_vector_type(8))) short short8;
typedef __attribute__((ext_vector_type(4))) float float4v;

#define MFMA16(a, b, c) __builtin_amdgcn_mfma_f32_16x16x32_bf16((a), (b), (c), 0, 0, 0)

__device__ __forceinline__ void glds16(const void* g, void* l) {
    __builtin_amdgcn_global_load_lds(
        (const __attribute__((address_space(1))) void*)g,
        (__attribute__((address_space(3))) void*)l, 16, 0, 0);
}

__device__ __forceinline__ unsigned int pk2(float a, float b) {
    __hip_bfloat162 h = __float22bfloat162_rn(make_float2(a, b));  // v_cvt_pk_bf16_f32
    union { __hip_bfloat162 h; unsigned int u; } v; v.h = h;
    return v.u;
}

__device__ __forceinline__ unsigned short f2bf(float x) {
    union { float f; unsigned int u; } v; v.f = x;
    unsigned int r = (v.u + 0x7FFFu + ((v.u >> 16) & 1u)) >> 16;   // RNE
    return (unsigned short)r;
}

__device__ __forceinline__ float bf2f(unsigned short b) {
    union { unsigned int u; float f; } v; v.u = ((unsigned int)b) << 16;
    return v.f;
}

// 8 contiguous fp32 -> bf16 bits (packed converts)
__device__ __forceinline__ short8 load8f(const float* p) {
    const float4 f0 = *(const float4*)p;
    const float4 f1 = *(const float4*)(p + 4);
    union { short8 s; unsigned int u[4]; } r;
    r.u[0] = pk2(f0.x, f0.y);
    r.u[1] = pk2(f0.z, f0.w);
    r.u[2] = pk2(f1.x, f1.y);
    r.u[3] = pk2(f1.z, f1.w);
    return r.s;
}

// ---------------------------------------------------------------------------
// x -> bf16 (blocks 0..4095) + rope table (blocks 4096..4351, into d_out tail)
__global__ __launch_bounds__(256) void convert_x_table(
    const float* __restrict__ in, __hip_bfloat16* __restrict__ out,
    float2* __restrict__ table)
{
    if (blockIdx.x < 4096) {
        const int idx = (blockIdx.x * 256 + threadIdx.x) * 8;
        *(short8*)(out + idx) = load8f(in + idx);
    } else {
        const int idx = (blockIdx.x - 4096) * 256 + threadIdx.x;   // 65536
        const int pos = idx >> 5, fi = idx & 31;
        const float f = exp2f(-(float)fi * (13.287712379549449f / 32.0f));
        float sn, cs;
        sincosf((float)pos * f, &sn, &cs);
        table[idx] = make_float2(cs, sn);
    }
}

// 4 weight matrices (1M elems each) in one launch: 512 blocks per matrix.
__global__ __launch_bounds__(256) void convert4_kernel(
    const float* __restrict__ a, const float* __restrict__ b,
    const float* __restrict__ c, const float* __restrict__ d,
    __hip_bfloat16* __restrict__ oa, __hip_bfloat16* __restrict__ ob,
    __hip_bfloat16* __restrict__ oc, __hip_bfloat16* __restrict__ od)
{
    const int m = blockIdx.x >> 9;
    const float* in = (m == 0) ? a : (m == 1) ? b : (m == 2) ? c : d;
    __hip_bfloat16* out = (m == 0) ? oa : (m == 1) ? ob : (m == 2) ? oc : od;
    const int idx = ((blockIdx.x & 511) * 256 + threadIdx.x) * 8;
    *(short8*)(out + idx) = load8f(in + idx);
}

// ---------------------------------------------------------------------------
// Fused QKV GEMM, 128x64 tiles, BK=64, swizzled staging. Grid 3072 with
// XCD-reuse remap: xcd=bid&7, j=bid>>3, bm=xcd+8*(j&7), bn=j>>3 — A-tile's
// 48 sharers co-located per XCD; 8 consecutive blocks share a B-tile.
// Q/K epilogue applies ROPE from registers; V -> swizzled LDS transpose.
// LDS 24 KiB, acc[4][2], VGPR 76 -> 6 blocks/CU.
// ---------------------------------------------------------------------------
template<int BBF>
__global__ __launch_bounds__(256) void qkv_gemm(
    const __hip_bfloat16* __restrict__ Abf,
    const void* __restrict__ Wq, const void* __restrict__ Wk, const void* __restrict__ Wv,
    __hip_bfloat16* __restrict__ Qp, __hip_bfloat16* __restrict__ Kp,
    __hip_bfloat16* __restrict__ Vt, const float2* __restrict__ table)
{
    __shared__ unsigned short smem[12288];   // A[0..8191] | B[8192..12287]; 24 KiB

    const int K = 1024;
    // XCD-reuse remap (8 XCDs, dispatch round-robin bid%8 -> XCD):
    const int xcd = blockIdx.x & 7;
    const int j = blockIdx.x >> 3;         // 0..383
    const int bm = xcd + 8 * (j & 7);      // 0..63 : all 48 bn of this bm on XCD 'xcd'
    const int bn = j >> 3;                 // 0..47 : 8 consecutive blocks share bn
    const int widx = bn >> 4;              // 0=Q 1=K 2=V
    const int bcol0 = (bn & 15) * 64;
    const void* W = (widx == 0) ? Wq : (widx == 1) ? Wk : Wv;

    const int tid = threadIdx.x;
    const int wave = tid >> 6, lane = tid & 63;
    const int wm = (wave >> 1) * 64, wn = (wave & 1) * 32;
    const int m16 = lane & 15, quad = lane >> 4;

    const int grow = lane >> 3;                              // glds16: 8 rows/instr
    const int gcolsw = ((lane & 7) ^ (lane >> 3)) * 8;       // pre-swizzled col
    const int srow = tid >> 3, scol = (tid & 7) * 8;         // fp32 register-path

    float4v acc[4][2] = {};

    for (int k0 = 0; k0 < K; k0 += 64) {
        short8 rb[2];
        if (!BBF) {
            const float* Wf = (const float*)W;
#pragma unroll
            for (int t = 0; t < 2; t++)
                rb[t] = load8f(Wf + (int64_t)(bcol0 + t * 32 + srow) * K + k0 + scol);
        }
        __syncthreads();
        {
            const __hip_bfloat16* g = Abf + (int64_t)(bm * 128 + wave * 32 + grow) * K + k0 + gcolsw;
#pragma unroll
            for (int t = 0; t < 4; t++)
                glds16(g + (int64_t)(t * 8) * K, &smem[(wave * 32 + t * 8) * 64]);
        }
        if (BBF) {
            const __hip_bfloat16* g = (const __hip_bfloat16*)W +
                (int64_t)(bcol0 + wave * 16 + grow) * K + k0 + gcolsw;
#pragma unroll
            for (int t = 0; t < 2; t++)
                glds16(g + (int64_t)(t * 8) * K, &smem[8192 + (wave * 16 + t * 8) * 64]);
        } else {
#pragma unroll
            for (int t = 0; t < 2; t++) {
                const int r = t * 32 + srow;
                *(short8*)&smem[8192 + r * 64 + (scol ^ ((r & 7) * 8))] = rb[t];
            }
        }
        __syncthreads();

#pragma unroll
        for (int kk = 0; kk < 2; kk++) {
            const int ksw = (kk * 32 + quad * 8) ^ ((m16 & 7) * 8);
            short8 af[4], bf[2];
#pragma unroll
            for (int i = 0; i < 4; i++)
                af[i] = *(const short8*)&smem[(wm + i * 16 + m16) * 64 + ksw];
#pragma unroll
            for (int j2 = 0; j2 < 2; j2++)
                bf[j2] = *(const short8*)&smem[8192 + (wn + j2 * 16 + m16) * 64 + ksw];
#pragma unroll
            for (int i = 0; i < 4; i++)
#pragma unroll
                for (int j2 = 0; j2 < 2; j2++)
                    acc[i][j2] = MFMA16(af[i], bf[j2], acc[i][j2]);
        }
    }

    if (widx == 2) {
        // ---- V: transpose through LDS (XOR swizzle, stride 128); 16 KiB ----
        __syncthreads();
#pragma unroll
        for (int i = 0; i < 4; i++)
#pragma unroll
            for (int j2 = 0; j2 < 2; j2++) {
                const int col = wn + j2 * 16 + m16;         // 0..63
                const int key = (col & 7) * 8;
#pragma unroll
                for (int r = 0; r < 4; r++) {
                    const int row = wm + i * 16 + quad * 4 + r;
                    smem[col * 128 + (row ^ key)] = f2bf(acc[i][j2][r]);
                }
            }
        __syncthreads();
        const int dc = tid >> 4;          // 0..15
        const int seg = (tid & 15) * 8;   // 0..120 (mult of 8 -> XOR stays contiguous)
#pragma unroll
        for (int pass = 0; pass < 4; pass++) {
            const int dcol = pass * 16 + dc;                // 0..63
            const short8 v = *(const short8*)&smem[dcol * 128 + (seg ^ ((dcol & 7) * 8))];
            *(short8*)((unsigned short*)Vt + (int64_t)(bcol0 + dcol) * 8192 + bm * 128 + seg) = v;
        }
    } else {
        // ---- Q/K: ROPE in registers, then plain store ----
        // C layout: col parity = m16&1 (lane-uniform); partner (col^1) in
        // lane^1 via __shfl_xor. out = v*cos + sgn*vp*sin; Q pre-scaled.
        __hip_bfloat16* dst = (widx == 0) ? Qp : Kp;
        const float scale = (widx == 0) ? 0.18033688011112042f : 1.0f;
        const float sgn = (m16 & 1) ? 1.0f : -1.0f;
        const int row0 = bm * 128 + wm + quad * 4;
        const int col0 = bcol0 + wn + m16;
#pragma unroll
        for (int i = 0; i < 4; i++)
#pragma unroll
            for (int j2 = 0; j2 < 2; j2++) {
                const int ifq = ((wn + j2 * 16 + m16) & 63) >> 1;  // pair idx in head
#pragma unroll
                for (int r = 0; r < 4; r++) {
                    const float v = acc[i][j2][r] * scale;
                    const float vp = __shfl_xor(v, 1);
                    const int row = row0 + i * 16 + r;
                    const float2 cs = table[(row & 2047) * 32 + ifq];
                    const float out = v * cs.x + sgn * vp * cs.y;
                    dst[(int64_t)row * 1024 + col0 + j2 * 16] = __float2bfloat16(out);
                }
            }
    }
}

// ---------------------------------------------------------------------------
// Output GEMM, BK=64: C[8192][1024] fp32 = A(bf16, glds16) * B^T.
// Swizzled staging. BM=128, BN=64 -> 1024 blocks; XCD-reuse remap.
// ---------------------------------------------------------------------------
template<int BBF>
__global__ __launch_bounds__(256) void gemm_o(
    const __hip_bfloat16* __restrict__ Abf, const void* __restrict__ B,
    float* __restrict__ C, int M, int N, int K)
{
    __shared__ __hip_bfloat16 lA[128 * 64];   // 16 KiB
    __shared__ __hip_bfloat16 lB[64 * 64];    //  8 KiB

    // XCD-reuse remap: grid 1024 = 64 bm x 16 bn.
    const int xcd = blockIdx.x & 7;
    const int j = blockIdx.x >> 3;        // 0..127
    const int bm = xcd + 8 * (j & 7);     // 0..63
    const int bn = j >> 3;                // 0..15
    const int tid = threadIdx.x;
    const int wave = tid >> 6, lane = tid & 63;
    const int wm = (wave >> 1) * 64, wn = (wave & 1) * 32;
    const int m16 = lane & 15, quad = lane >> 4;
    const int grow = lane >> 3;
    const int gcolsw = ((lane & 7) ^ (lane >> 3)) * 8;
    const int srow = tid >> 3, scol = (tid & 7) * 8;     // fp32 path: 32 rows x 64 cols

    float4v acc[4][2] = {};

    for (int k0 = 0; k0 < K; k0 += 64) {
        short8 rb[2];
        if (!BBF) {
            const float* Bf = (const float*)B;
#pragma unroll
            for (int t = 0; t < 2; t++)
                rb[t] = load8f(Bf + (int64_t)(bn * 64 + t * 32 + srow) * K + k0 + scol);
        }
        __syncthreads();
        {
            const __hip_bfloat16* g = Abf + (int64_t)(bm * 128 + wave * 32 + grow) * K + k0 + gcolsw;
#pragma unroll
            for (int t = 0; t < 4; t++)
                glds16(g + (int64_t)(t * 8) * K, &lA[(wave * 32 + t * 8) * 64]);
        }
        if (BBF) {
            const __hip_bfloat16* g = (const __hip_bfloat16*)B +
                (int64_t)(bn * 64 + wave * 16 + grow) * K + k0 + gcolsw;
#pragma unroll
            for (int t = 0; t < 2; t++)
                glds16(g + (int64_t)(t * 8) * K, &lB[(wave * 16 + t * 8) * 64]);
        } else {
#pragma unroll
            for (int t = 0; t < 2; t++) {
                const int r = t * 32 + srow;
                *(short8*)&lB[r * 64 + (scol ^ ((r & 7) * 8))] = rb[t];
            }
        }
        __syncthreads();

#pragma unroll
        for (int kk = 0; kk < 2; kk++) {
            const int ksw = (kk * 32 + quad * 8) ^ ((m16 & 7) * 8);
            short8 af[4], bf[2];
#pragma unroll
            for (int i = 0; i < 4; i++)
                af[i] = *(const short8*)&lA[(wm + i * 16 + m16) * 64 + ksw];
#pragma unroll
            for (int j2 = 0; j2 < 2; j2++)
                bf[j2] = *(const short8*)&lB[(wn + j2 * 16 + m16) * 64 + ksw];
#pragma unroll
            for (int i = 0; i < 4; i++)
#pragma unroll
                for (int j2 = 0; j2 < 2; j2++)
                    acc[i][j2] = MFMA16(af[i], bf[j2], acc[i][j2]);
        }
    }

    const int row0 = bm * 128 + wm + quad * 4;
    const int col0 = bn * 64 + wn + m16;
#pragma unroll
    for (int i = 0; i < 4; i++)
#pragma unroll
        for (int j2 = 0; j2 < 2; j2++)
#pragma unroll
            for (int r = 0; r < 4; r++)
                C[(int64_t)(row0 + i * 16 + r) * N + col0 + j2 * 16] = acc[i][j2][r];
}

// ---------------------------------------------------------------------------
// Flash attention, causal, fixed-max softmax (Q pre-scaled by log2e/8;
// p = exp2(score) via RAW v_exp_f32). Block = 4 waves x 32 Q rows = 128;
// Bc = 64. S^T-MFMA: st[mi][ni] = MFMA(K-frag, Q-frag) gives S^T in
// C-layout -> pk2 + ds_write_b64 into lP (XOR swizzle key, r-invariant).
// PV reads lP with the proven 0-conflict b128 pattern. lsum VALU-accumulated
// per (ni, m16); epilogue: 2 shuffles + shfl-gather of 1/l. VGPR 76,
// 5 blocks/CU. UNTOUCHED since R16.
// ---------------------------------------------------------------------------
__global__ __launch_bounds__(256) void attn_kernel(
    const __hip_bfloat16* __restrict__ Q,
    const __hip_bfloat16* __restrict__ Kg,
    const __hip_bfloat16* __restrict__ Vt,
    __hip_bfloat16* __restrict__ O,
    int S, int BS)
{
    // g -> qt permutation: residency groups {x, x+4, x+8, x+12} each sum to
    // 30 kt-units -> per-CU balanced; heavy blocks first. bh stays bid&63 so
    // all qt-blocks of one (b,h) keep sharing an XCD (K/V L2-local).
    const int g = blockIdx.x >> 6;        // 0..15 (S=2048)
    const int qt = (g < 4) ? 15 - g : (g < 8) ? 11 - g : (g < 12) ? g : g - 12;
    const int bh = blockIdx.x & 63;
    const int b = bh >> 4, h = bh & 15;
    const int tid = threadIdx.x;
    const int wave = tid >> 6, lane = tid & 63;
    const int m16 = lane & 15, quad = lane >> 4;

    __shared__ __hip_bfloat16 lK[64 * 64];
    __shared__ __hip_bfloat16 lV[64 * 64];        // Vt tile: [d][kv]
    __shared__ __hip_bfloat16 lP[4][32 * 64];     // total LDS = 32768 B

    const int qrow0 = qt * 128 + wave * 32;
    const int64_t rowbase = (int64_t)b * S;

    // Q frags (B-operand of the S^T MFMA): aq[ni][ks]
    short8 aq[2][2];
#pragma unroll
    for (int i = 0; i < 2; i++) {
        const __hip_bfloat16* qp = Q + (rowbase + qrow0 + i * 16 + m16) * 1024 + h * 64 + quad * 8;
        aq[i][0] = *(const short8*)qp;
        aq[i][1] = *(const short8*)(qp + 32);
    }

    float lsum[2] = {0.f, 0.f};                   // per (ni, lane m16) partials
    float4v o_acc[2][4] = {};

    const int srow = tid >> 3;
    const int scol = (tid & 7) * 8;

    const int ktmax_blk = 2 * qt + 1;
    const int ktmax_w = 2 * qt + (wave >> 1);
    const int k8 = (m16 & 7) * 8;                 // lP swizzle key (elems)

    short8 pk0, pk1, pv0, pv1;
#define PREFETCH(KT)                                                                          \
    do {                                                                                      \
        pk0 = *(const short8*)(Kg + (rowbase + (KT) * 64 + srow) * 1024 + h * 64 + scol);     \
        pk1 = *(const short8*)(Kg + (rowbase + (KT) * 64 + srow + 32) * 1024 + h * 64 + scol);\
        pv0 = *(const short8*)(Vt + (int64_t)(h * 64 + srow) * BS + rowbase + (KT) * 64 + scol);      \
        pv1 = *(const short8*)(Vt + (int64_t)(h * 64 + srow + 32) * BS + rowbase + (KT) * 64 + scol); \
    } while (0)

    PREFETCH(0);

    for (int kt = 0; kt <= ktmax_blk; kt++) {
        __syncthreads();
        *(short8*)&lK[srow * 64 + (scol ^ ((srow & 7) * 8))] = pk0;
        *(short8*)&lK[(srow + 32) * 64 + (scol ^ (((srow + 32) & 7) * 8))] = pk1;
        *(short8*)&lV[srow * 64 + (scol ^ ((srow & 7) * 8))] = pv0;
        *(short8*)&lV[(srow + 32) * 64 + (scol ^ (((srow + 32) & 7) * 8))] = pv1;
        __syncthreads();

        if (kt < ktmax_blk) PREFETCH(kt + 1);

        if (kt <= ktmax_w) {
            // S^T = K Q^T : st[mi][ni], C-layout row = kv, col = qrow
            float4v st[4][2] = {};
#pragma unroll
            for (int mi = 0; mi < 4; mi++) {
                const int n = mi * 16 + m16;
                const int sw = (n & 7) * 8;
                short8 k0 = *(const short8*)&lK[n * 64 + ((quad * 8) ^ sw)];
                short8 k1 = *(const short8*)&lK[n * 64 + ((32 + quad * 8) ^ sw)];
#pragma unroll
                for (int ni = 0; ni < 2; ni++) {
                    st[mi][ni] = MFMA16(k0, aq[ni][0], st[mi][ni]);
                    st[mi][ni] = MFMA16(k1, aq[ni][1], st[mi][ni]);
                }
            }

            // exp2 (raw v_exp_f32), causal mask, lsum, packed b64 write to lP
            const bool need_mask = (kt * 64 + 63 > qrow0);
#pragma unroll
            for (int ni = 0; ni < 2; ni++) {
                const int qg = qrow0 + ni * 16 + m16;
#pragma unroll
                for (int mi = 0; mi < 4; mi++) {
                    float p[4];
#pragma unroll
                    for (int r = 0; r < 4; r++) {
                        p[r] = __builtin_amdgcn_exp2f(st[mi][ni][r]);
                        if (need_mask) {
                            const int kvg = kt * 64 + mi * 16 + quad * 4 + r;
                            if (kvg > qg) p[r] = 0.0f;
                        }
                    }
                    lsum[ni] += (p[0] + p[1]) + (p[2] + p[3]);
                    uint2 w;
                    w.x = pk2(p[0], p[1]);
                    w.y = pk2(p[2], p[3]);
                    *(uint2*)&lP[wave][(ni * 16 + m16) * 64 + ((mi * 16 + quad * 4) ^ k8)] = w;
                }
            }

            // O += P V (lP wave-private; lgkmcnt ordering suffices)
            short8 ap[2][2];
#pragma unroll
            for (int i = 0; i < 2; i++)
#pragma unroll
                for (int ks = 0; ks < 2; ks++)
                    ap[i][ks] = *(const short8*)
                        &lP[wave][(i * 16 + m16) * 64 + ((ks * 32 + quad * 8) ^ k8)];
#pragma unroll
            for (int jd = 0; jd < 4; jd++) {
                const int d = jd * 16 + m16;
                const int sw = (d & 7) * 8;
                short8 b0 = *(const short8*)&lV[d * 64 + ((quad * 8) ^ sw)];
                short8 b1 = *(const short8*)&lV[d * 64 + ((32 + quad * 8) ^ sw)];
#pragma unroll
                for (int i = 0; i < 2; i++) {
                    o_acc[i][jd] = MFMA16(ap[i][0], b0, o_acc[i][jd]);
                    o_acc[i][jd] = MFMA16(ap[i][1], b1, o_acc[i][jd]);
                }
            }
        }
    }
#undef PREFETCH

    // l reduction: after xor16+xor32 every lane holds its m16-column's full
    // sum; invert once, then shfl-gather 1/l for the O-store lanes (no LDS).
    float rinv[2];
#pragma unroll
    for (int ni = 0; ni < 2; ni++) {
        float v = lsum[ni];
        v += __shfl_xor(v, 16);
        v += __shfl_xor(v, 32);
        rinv[ni] = 1.0f / v;
    }
    float ri[2][4];
#pragma unroll
    for (int i = 0; i < 2; i++)
#pragma unroll
        for (int r = 0; r < 4; r++)
            ri[i][r] = __shfl(rinv[i], quad * 4 + r);   // lane p holds column p

#pragma unroll
    for (int i = 0; i < 2; i++)
#pragma unroll
        for (int jd = 0; jd < 4; jd++)
#pragma unroll
            for (int r = 0; r < 4; r++) {
                const int row = qrow0 + i * 16 + quad * 4 + r;
                O[(rowbase + row) * 1024 + h * 64 + jd * 16 + m16] =
                    __float2bfloat16(o_acc[i][jd][r] * ri[i][r]);
            }
}

// ---------------------------------------------------------------------------
extern "C" void kernel_launch(void* const* d_in, const int* in_sizes, int n_in,
                              void* d_out, int out_size, void* d_ws, size_t ws_size,
                              hipStream_t stream)
{
    const float* x  = (const float*)d_in[0];
    const float* qw = (const float*)d_in[1];
    const float* kw = (const float*)d_in[2];
    const float* vw = (const float*)d_in[3];
    const float* ow = (const float*)d_in[4];

    const int BS = 8192, D = 1024, S = 2048;
    const size_t MiB = 1024 * 1024;

    char* ws = (char*)d_ws;
    __hip_bfloat16* xb  = (__hip_bfloat16*)(ws);
    __hip_bfloat16* Qb  = (__hip_bfloat16*)(ws + 16 * MiB); // also AO
    __hip_bfloat16* Kb  = (__hip_bfloat16*)(ws + 32 * MiB);
    __hip_bfloat16* Vtb = (__hip_bfloat16*)(ws + 48 * MiB);
    __hip_bfloat16* wqb = (__hip_bfloat16*)(ws + 64 * MiB);
    __hip_bfloat16* wkb = (__hip_bfloat16*)(ws + 66 * MiB);
    __hip_bfloat16* wvb = (__hip_bfloat16*)(ws + 68 * MiB);
    __hip_bfloat16* wob = (__hip_bfloat16*)(ws + 70 * MiB);
    // rope table lives in d_out's tail (512 KB at +31 MiB): written by
    // convert_x_table, read by qkv_gemm, dead before gemm_o overwrites d_out.
    float2* table = (float2*)((char*)d_out + 31 * MiB);
    const bool wbf = ws_size >= 72 * MiB;                   // fast path fits?

    dim3 blk(256);
    convert_x_table<<<4096 + 256, blk, 0, stream>>>(x, xb, table);
    if (wbf) {
        convert4_kernel<<<4 * (D * D) / 2048, blk, 0, stream>>>(
            qw, kw, vw, ow, wqb, wkb, wvb, wob);
        qkv_gemm<1><<<64 * 48, blk, 0, stream>>>(xb, wqb, wkb, wvb, Qb, Kb, Vtb, table);
    } else {
        qkv_gemm<0><<<64 * 48, blk, 0, stream>>>(xb, qw, kw, vw, Qb, Kb, Vtb, table);
    }
    attn_kernel<<<4 * 16 * (S / 128), blk, 0, stream>>>(Qb, Kb, Vtb, Qb /*AO*/, S, BS);
    if (wbf) gemm_o<1><<<(BS / 128) * (D / 64), blk, 0, stream>>>(Qb, wob, (float*)d_out, BS, D, D);
    else     gemm_o<0><<<(BS / 128) * (D / 64), blk, 0, stream>>>(Qb, ow,  (float*)d_out, BS, D, D);
}

// Round 17
// 248.496 us; speedup vs baseline: 1.0697x; 1.0081x over previous
//
#include <hip/hip_runtime.h>
#include <hip/hip_bf16.h>
#include <cstdint>

// B=4, S=2048, D=1024, NH=16, DK=64. Inputs fp32, output fp32.
// Pipeline (5 launches):
//   convert_x_table: xb = bf16(x) + rope cos/sin table (into d_out tail)
//   convert4: weights -> bf16 (fast path)
//   qkv_gemm (3072 blocks, 128x64, BK=64, swizzled staging, XCD-reuse
//            remap): Q|K stores with fused ROPE; V -> Vt transpose.
//   attn: causal flash, raw-v_exp_f32 softmax, S^T-MFMA.
//   gemm_o: BK=64, swizzled, XCD-reuse remap, 128x64 tiles -> fp32 out.
//
// R22 post-mortem: XCD-reuse remap confirmed by counters (qkv FETCH 86->
// 48.5MB, dur 81.2->74.3 same-container). Total 250.5 ~ noise band of the
// R18 best (247.6). Session ledger 319.9 -> ~248-250 (-22%). Surviving
// wins: qt-permutation+32KiB LDS, staging swizzle+BK=64, raw v_exp_f32,
// 128x64 packing, rope fusion, XCD-reuse remap. Refuted+reverted:
// lacc-MFMA (occupancy cliff), launch-bounds caps (spills), 2-phase stage
// (TLP covers drain), convert merge. No kernel at a HW roofline (qkv
// Mfma 29/VALU 22/HBM 17; attn VALU 52) — both issue/latency-bound in the
// 2-barrier structure; remaining structural escapes cost occupancy per
// R12/R13/R19 measurements. R23 = R22 unchanged (bank best-known).

typedef __attribute__((ext_vector_type(8))) short short8;
typedef __attribute__((ext_vector_type(4))) float float4v;

#define MFMA16(a, b, c) __builtin_amdgcn_mfma_f32_16x16x32_bf16((a), (b), (c), 0, 0, 0)

__device__ __forceinline__ void glds16(const void* g, void* l) {
    __builtin_amdgcn_global_load_lds(
        (const __attribute__((address_space(1))) void*)g,
        (__attribute__((address_space(3))) void*)l, 16, 0, 0);
}

__device__ __forceinline__ unsigned int pk2(float a, float b) {
    __hip_bfloat162 h = __float22bfloat162_rn(make_float2(a, b));  // v_cvt_pk_bf16_f32
    union { __hip_bfloat162 h; unsigned int u; } v; v.h = h;
    return v.u;
}

__device__ __forceinline__ unsigned short f2bf(float x) {
    union { float f; unsigned int u; } v; v.f = x;
    unsigned int r = (v.u + 0x7FFFu + ((v.u >> 16) & 1u)) >> 16;   // RNE
    return (unsigned short)r;
}

__device__ __forceinline__ float bf2f(unsigned short b) {
    union { unsigned int u; float f; } v; v.u = ((unsigned int)b) << 16;
    return v.f;
}

// 8 contiguous fp32 -> bf16 bits (packed converts)
__device__ __forceinline__ short8 load8f(const float* p) {
    const float4 f0 = *(const float4*)p;
    const float4 f1 = *(const float4*)(p + 4);
    union { short8 s; unsigned int u[4]; } r;
    r.u[0] = pk2(f0.x, f0.y);
    r.u[1] = pk2(f0.z, f0.w);
    r.u[2] = pk2(f1.x, f1.y);
    r.u[3] = pk2(f1.z, f1.w);
    return r.s;
}

// ---------------------------------------------------------------------------
// x -> bf16 (blocks 0..4095) + rope table (blocks 4096..4351, into d_out tail)
__global__ __launch_bounds__(256) void convert_x_table(
    const float* __restrict__ in, __hip_bfloat16* __restrict__ out,
    float2* __restrict__ table)
{
    if (blockIdx.x < 4096) {
        const int idx = (blockIdx.x * 256 + threadIdx.x) * 8;
        *(short8*)(out + idx) = load8f(in + idx);
    } else {
        const int idx = (blockIdx.x - 4096) * 256 + threadIdx.x;   // 65536
        const int pos = idx >> 5, fi = idx & 31;
        const float f = exp2f(-(float)fi * (13.287712379549449f / 32.0f));
        float sn, cs;
        sincosf((float)pos * f, &sn, &cs);
        table[idx] = make_float2(cs, sn);
    }
}

// 4 weight matrices (1M elems each) in one launch: 512 blocks per matrix.
__global__ __launch_bounds__(256) void convert4_kernel(
    const float* __restrict__ a, const float* __restrict__ b,
    const float* __restrict__ c, const float* __restrict__ d,
    __hip_bfloat16* __restrict__ oa, __hip_bfloat16* __restrict__ ob,
    __hip_bfloat16* __restrict__ oc, __hip_bfloat16* __restrict__ od)
{
    const int m = blockIdx.x >> 9;
    const float* in = (m == 0) ? a : (m == 1) ? b : (m == 2) ? c : d;
    __hip_bfloat16* out = (m == 0) ? oa : (m == 1) ? ob : (m == 2) ? oc : od;
    const int idx = ((blockIdx.x & 511) * 256 + threadIdx.x) * 8;
    *(short8*)(out + idx) = load8f(in + idx);
}

// ---------------------------------------------------------------------------
// Fused QKV GEMM, 128x64 tiles, BK=64, swizzled staging. Grid 3072 with
// XCD-reuse remap: xcd=bid&7, j=bid>>3, bm=xcd+8*(j&7), bn=j>>3 — A-tile's
// 48 sharers co-located per XCD; 8 consecutive blocks share a B-tile.
// Q/K epilogue applies ROPE from registers; V -> swizzled LDS transpose.
// LDS 24 KiB, acc[4][2], VGPR 76 -> 6 blocks/CU.
// ---------------------------------------------------------------------------
template<int BBF>
__global__ __launch_bounds__(256) void qkv_gemm(
    const __hip_bfloat16* __restrict__ Abf,
    const void* __restrict__ Wq, const void* __restrict__ Wk, const void* __restrict__ Wv,
    __hip_bfloat16* __restrict__ Qp, __hip_bfloat16* __restrict__ Kp,
    __hip_bfloat16* __restrict__ Vt, const float2* __restrict__ table)
{
    __shared__ unsigned short smem[12288];   // A[0..8191] | B[8192..12287]; 24 KiB

    const int K = 1024;
    // XCD-reuse remap (8 XCDs, dispatch round-robin bid%8 -> XCD):
    const int xcd = blockIdx.x & 7;
    const int j = blockIdx.x >> 3;         // 0..383
    const int bm = xcd + 8 * (j & 7);      // 0..63 : all 48 bn of this bm on XCD 'xcd'
    const int bn = j >> 3;                 // 0..47 : 8 consecutive blocks share bn
    const int widx = bn >> 4;              // 0=Q 1=K 2=V
    const int bcol0 = (bn & 15) * 64;
    const void* W = (widx == 0) ? Wq : (widx == 1) ? Wk : Wv;

    const int tid = threadIdx.x;
    const int wave = tid >> 6, lane = tid & 63;
    const int wm = (wave >> 1) * 64, wn = (wave & 1) * 32;
    const int m16 = lane & 15, quad = lane >> 4;

    const int grow = lane >> 3;                              // glds16: 8 rows/instr
    const int gcolsw = ((lane & 7) ^ (lane >> 3)) * 8;       // pre-swizzled col
    const int srow = tid >> 3, scol = (tid & 7) * 8;         // fp32 register-path

    float4v acc[4][2] = {};

    for (int k0 = 0; k0 < K; k0 += 64) {
        short8 rb[2];
        if (!BBF) {
            const float* Wf = (const float*)W;
#pragma unroll
            for (int t = 0; t < 2; t++)
                rb[t] = load8f(Wf + (int64_t)(bcol0 + t * 32 + srow) * K + k0 + scol);
        }
        __syncthreads();
        {
            const __hip_bfloat16* g = Abf + (int64_t)(bm * 128 + wave * 32 + grow) * K + k0 + gcolsw;
#pragma unroll
            for (int t = 0; t < 4; t++)
                glds16(g + (int64_t)(t * 8) * K, &smem[(wave * 32 + t * 8) * 64]);
        }
        if (BBF) {
            const __hip_bfloat16* g = (const __hip_bfloat16*)W +
                (int64_t)(bcol0 + wave * 16 + grow) * K + k0 + gcolsw;
#pragma unroll
            for (int t = 0; t < 2; t++)
                glds16(g + (int64_t)(t * 8) * K, &smem[8192 + (wave * 16 + t * 8) * 64]);
        } else {
#pragma unroll
            for (int t = 0; t < 2; t++) {
                const int r = t * 32 + srow;
                *(short8*)&smem[8192 + r * 64 + (scol ^ ((r & 7) * 8))] = rb[t];
            }
        }
        __syncthreads();

#pragma unroll
        for (int kk = 0; kk < 2; kk++) {
            const int ksw = (kk * 32 + quad * 8) ^ ((m16 & 7) * 8);
            short8 af[4], bf[2];
#pragma unroll
            for (int i = 0; i < 4; i++)
                af[i] = *(const short8*)&smem[(wm + i * 16 + m16) * 64 + ksw];
#pragma unroll
            for (int j2 = 0; j2 < 2; j2++)
                bf[j2] = *(const short8*)&smem[8192 + (wn + j2 * 16 + m16) * 64 + ksw];
#pragma unroll
            for (int i = 0; i < 4; i++)
#pragma unroll
                for (int j2 = 0; j2 < 2; j2++)
                    acc[i][j2] = MFMA16(af[i], bf[j2], acc[i][j2]);
        }
    }

    if (widx == 2) {
        // ---- V: transpose through LDS (XOR swizzle, stride 128); 16 KiB ----
        __syncthreads();
#pragma unroll
        for (int i = 0; i < 4; i++)
#pragma unroll
            for (int j2 = 0; j2 < 2; j2++) {
                const int col = wn + j2 * 16 + m16;         // 0..63
                const int key = (col & 7) * 8;
#pragma unroll
                for (int r = 0; r < 4; r++) {
                    const int row = wm + i * 16 + quad * 4 + r;
                    smem[col * 128 + (row ^ key)] = f2bf(acc[i][j2][r]);
                }
            }
        __syncthreads();
        const int dc = tid >> 4;          // 0..15
        const int seg = (tid & 15) * 8;   // 0..120 (mult of 8 -> XOR stays contiguous)
#pragma unroll
        for (int pass = 0; pass < 4; pass++) {
            const int dcol = pass * 16 + dc;                // 0..63
            const short8 v = *(const short8*)&smem[dcol * 128 + (seg ^ ((dcol & 7) * 8))];
            *(short8*)((unsigned short*)Vt + (int64_t)(bcol0 + dcol) * 8192 + bm * 128 + seg) = v;
        }
    } else {
        // ---- Q/K: ROPE in registers, then plain store ----
        // C layout: col parity = m16&1 (lane-uniform); partner (col^1) in
        // lane^1 via __shfl_xor. out = v*cos + sgn*vp*sin; Q pre-scaled.
        __hip_bfloat16* dst = (widx == 0) ? Qp : Kp;
        const float scale = (widx == 0) ? 0.18033688011112042f : 1.0f;
        const float sgn = (m16 & 1) ? 1.0f : -1.0f;
        const int row0 = bm * 128 + wm + quad * 4;
        const int col0 = bcol0 + wn + m16;
#pragma unroll
        for (int i = 0; i < 4; i++)
#pragma unroll
            for (int j2 = 0; j2 < 2; j2++) {
                const int ifq = ((wn + j2 * 16 + m16) & 63) >> 1;  // pair idx in head
#pragma unroll
                for (int r = 0; r < 4; r++) {
                    const float v = acc[i][j2][r] * scale;
                    const float vp = __shfl_xor(v, 1);
                    const int row = row0 + i * 16 + r;
                    const float2 cs = table[(row & 2047) * 32 + ifq];
                    const float out = v * cs.x + sgn * vp * cs.y;
                    dst[(int64_t)row * 1024 + col0 + j2 * 16] = __float2bfloat16(out);
                }
            }
    }
}

// ---------------------------------------------------------------------------
// Output GEMM, BK=64: C[8192][1024] fp32 = A(bf16, glds16) * B^T.
// Swizzled staging. BM=128, BN=64 -> 1024 blocks; XCD-reuse remap.
// ---------------------------------------------------------------------------
template<int BBF>
__global__ __launch_bounds__(256) void gemm_o(
    const __hip_bfloat16* __restrict__ Abf, const void* __restrict__ B,
    float* __restrict__ C, int M, int N, int K)
{
    __shared__ __hip_bfloat16 lA[128 * 64];   // 16 KiB
    __shared__ __hip_bfloat16 lB[64 * 64];    //  8 KiB

    // XCD-reuse remap: grid 1024 = 64 bm x 16 bn.
    const int xcd = blockIdx.x & 7;
    const int j = blockIdx.x >> 3;        // 0..127
    const int bm = xcd + 8 * (j & 7);     // 0..63
    const int bn = j >> 3;                // 0..15
    const int tid = threadIdx.x;
    const int wave = tid >> 6, lane = tid & 63;
    const int wm = (wave >> 1) * 64, wn = (wave & 1) * 32;
    const int m16 = lane & 15, quad = lane >> 4;
    const int grow = lane >> 3;
    const int gcolsw = ((lane & 7) ^ (lane >> 3)) * 8;
    const int srow = tid >> 3, scol = (tid & 7) * 8;     // fp32 path: 32 rows x 64 cols

    float4v acc[4][2] = {};

    for (int k0 = 0; k0 < K; k0 += 64) {
        short8 rb[2];
        if (!BBF) {
            const float* Bf = (const float*)B;
#pragma unroll
            for (int t = 0; t < 2; t++)
                rb[t] = load8f(Bf + (int64_t)(bn * 64 + t * 32 + srow) * K + k0 + scol);
        }
        __syncthreads();
        {
            const __hip_bfloat16* g = Abf + (int64_t)(bm * 128 + wave * 32 + grow) * K + k0 + gcolsw;
#pragma unroll
            for (int t = 0; t < 4; t++)
                glds16(g + (int64_t)(t * 8) * K, &lA[(wave * 32 + t * 8) * 64]);
        }
        if (BBF) {
            const __hip_bfloat16* g = (const __hip_bfloat16*)B +
                (int64_t)(bn * 64 + wave * 16 + grow) * K + k0 + gcolsw;
#pragma unroll
            for (int t = 0; t < 2; t++)
                glds16(g + (int64_t)(t * 8) * K, &lB[(wave * 16 + t * 8) * 64]);
        } else {
#pragma unroll
            for (int t = 0; t < 2; t++) {
                const int r = t * 32 + srow;
                *(short8*)&lB[r * 64 + (scol ^ ((r & 7) * 8))] = rb[t];
            }
        }
        __syncthreads();

#pragma unroll
        for (int kk = 0; kk < 2; kk++) {
            const int ksw = (kk * 32 + quad * 8) ^ ((m16 & 7) * 8);
            short8 af[4], bf[2];
#pragma unroll
            for (int i = 0; i < 4; i++)
                af[i] = *(const short8*)&lA[(wm + i * 16 + m16) * 64 + ksw];
#pragma unroll
            for (int j2 = 0; j2 < 2; j2++)
                bf[j2] = *(const short8*)&lB[(wn + j2 * 16 + m16) * 64 + ksw];
#pragma unroll
            for (int i = 0; i < 4; i++)
#pragma unroll
                for (int j2 = 0; j2 < 2; j2++)
                    acc[i][j2] = MFMA16(af[i], bf[j2], acc[i][j2]);
        }
    }

    const int row0 = bm * 128 + wm + quad * 4;
    const int col0 = bn * 64 + wn + m16;
#pragma unroll
    for (int i = 0; i < 4; i++)
#pragma unroll
        for (int j2 = 0; j2 < 2; j2++)
#pragma unroll
            for (int r = 0; r < 4; r++)
                C[(int64_t)(row0 + i * 16 + r) * N + col0 + j2 * 16] = acc[i][j2][r];
}

// ---------------------------------------------------------------------------
// Flash attention, causal, fixed-max softmax (Q pre-scaled by log2e/8;
// p = exp2(score) via RAW v_exp_f32). Block = 4 waves x 32 Q rows = 128;
// Bc = 64. S^T-MFMA: st[mi][ni] = MFMA(K-frag, Q-frag) gives S^T in
// C-layout -> pk2 + ds_write_b64 into lP (XOR swizzle key, r-invariant).
// PV reads lP with the proven 0-conflict b128 pattern. lsum VALU-accumulated
// per (ni, m16); epilogue: 2 shuffles + shfl-gather of 1/l. VGPR 76,
// 5 blocks/CU. UNTOUCHED since R16.
// ---------------------------------------------------------------------------
__global__ __launch_bounds__(256) void attn_kernel(
    const __hip_bfloat16* __restrict__ Q,
    const __hip_bfloat16* __restrict__ Kg,
    const __hip_bfloat16* __restrict__ Vt,
    __hip_bfloat16* __restrict__ O,
    int S, int BS)
{
    // g -> qt permutation: residency groups {x, x+4, x+8, x+12} each sum to
    // 30 kt-units -> per-CU balanced; heavy blocks first. bh stays bid&63 so
    // all qt-blocks of one (b,h) keep sharing an XCD (K/V L2-local).
    const int g = blockIdx.x >> 6;        // 0..15 (S=2048)
    const int qt = (g < 4) ? 15 - g : (g < 8) ? 11 - g : (g < 12) ? g : g - 12;
    const int bh = blockIdx.x & 63;
    const int b = bh >> 4, h = bh & 15;
    const int tid = threadIdx.x;
    const int wave = tid >> 6, lane = tid & 63;
    const int m16 = lane & 15, quad = lane >> 4;

    __shared__ __hip_bfloat16 lK[64 * 64];
    __shared__ __hip_bfloat16 lV[64 * 64];        // Vt tile: [d][kv]
    __shared__ __hip_bfloat16 lP[4][32 * 64];     // total LDS = 32768 B

    const int qrow0 = qt * 128 + wave * 32;
    const int64_t rowbase = (int64_t)b * S;

    // Q frags (B-operand of the S^T MFMA): aq[ni][ks]
    short8 aq[2][2];
#pragma unroll
    for (int i = 0; i < 2; i++) {
        const __hip_bfloat16* qp = Q + (rowbase + qrow0 + i * 16 + m16) * 1024 + h * 64 + quad * 8;
        aq[i][0] = *(const short8*)qp;
        aq[i][1] = *(const short8*)(qp + 32);
    }

    float lsum[2] = {0.f, 0.f};                   // per (ni, lane m16) partials
    float4v o_acc[2][4] = {};

    const int srow = tid >> 3;
    const int scol = (tid & 7) * 8;

    const int ktmax_blk = 2 * qt + 1;
    const int ktmax_w = 2 * qt + (wave >> 1);
    const int k8 = (m16 & 7) * 8;                 // lP swizzle key (elems)

    short8 pk0, pk1, pv0, pv1;
#define PREFETCH(KT)                                                                          \
    do {                                                                                      \
        pk0 = *(const short8*)(Kg + (rowbase + (KT) * 64 + srow) * 1024 + h * 64 + scol);     \
        pk1 = *(const short8*)(Kg + (rowbase + (KT) * 64 + srow + 32) * 1024 + h * 64 + scol);\
        pv0 = *(const short8*)(Vt + (int64_t)(h * 64 + srow) * BS + rowbase + (KT) * 64 + scol);      \
        pv1 = *(const short8*)(Vt + (int64_t)(h * 64 + srow + 32) * BS + rowbase + (KT) * 64 + scol); \
    } while (0)

    PREFETCH(0);

    for (int kt = 0; kt <= ktmax_blk; kt++) {
        __syncthreads();
        *(short8*)&lK[srow * 64 + (scol ^ ((srow & 7) * 8))] = pk0;
        *(short8*)&lK[(srow + 32) * 64 + (scol ^ (((srow + 32) & 7) * 8))] = pk1;
        *(short8*)&lV[srow * 64 + (scol ^ ((srow & 7) * 8))] = pv0;
        *(short8*)&lV[(srow + 32) * 64 + (scol ^ (((srow + 32) & 7) * 8))] = pv1;
        __syncthreads();

        if (kt < ktmax_blk) PREFETCH(kt + 1);

        if (kt <= ktmax_w) {
            // S^T = K Q^T : st[mi][ni], C-layout row = kv, col = qrow
            float4v st[4][2] = {};
#pragma unroll
            for (int mi = 0; mi < 4; mi++) {
                const int n = mi * 16 + m16;
                const int sw = (n & 7) * 8;
                short8 k0 = *(const short8*)&lK[n * 64 + ((quad * 8) ^ sw)];
                short8 k1 = *(const short8*)&lK[n * 64 + ((32 + quad * 8) ^ sw)];
#pragma unroll
                for (int ni = 0; ni < 2; ni++) {
                    st[mi][ni] = MFMA16(k0, aq[ni][0], st[mi][ni]);
                    st[mi][ni] = MFMA16(k1, aq[ni][1], st[mi][ni]);
                }
            }

            // exp2 (raw v_exp_f32), causal mask, lsum, packed b64 write to lP
            const bool need_mask = (kt * 64 + 63 > qrow0);
#pragma unroll
            for (int ni = 0; ni < 2; ni++) {
                const int qg = qrow0 + ni * 16 + m16;
#pragma unroll
                for (int mi = 0; mi < 4; mi++) {
                    float p[4];
#pragma unroll
                    for (int r = 0; r < 4; r++) {
                        p[r] = __builtin_amdgcn_exp2f(st[mi][ni][r]);
                        if (need_mask) {
                            const int kvg = kt * 64 + mi * 16 + quad * 4 + r;
                            if (kvg > qg) p[r] = 0.0f;
                        }
                    }
                    lsum[ni] += (p[0] + p[1]) + (p[2] + p[3]);
                    uint2 w;
                    w.x = pk2(p[0], p[1]);
                    w.y = pk2(p[2], p[3]);
                    *(uint2*)&lP[wave][(ni * 16 + m16) * 64 + ((mi * 16 + quad * 4) ^ k8)] = w;
                }
            }

            // O += P V (lP wave-private; lgkmcnt ordering suffices)
            short8 ap[2][2];
#pragma unroll
            for (int i = 0; i < 2; i++)
#pragma unroll
                for (int ks = 0; ks < 2; ks++)
                    ap[i][ks] = *(const short8*)
                        &lP[wave][(i * 16 + m16) * 64 + ((ks * 32 + quad * 8) ^ k8)];
#pragma unroll
            for (int jd = 0; jd < 4; jd++) {
                const int d = jd * 16 + m16;
                const int sw = (d & 7) * 8;
                short8 b0 = *(const short8*)&lV[d * 64 + ((quad * 8) ^ sw)];
                short8 b1 = *(const short8*)&lV[d * 64 + ((32 + quad * 8) ^ sw)];
#pragma unroll
                for (int i = 0; i < 2; i++) {
                    o_acc[i][jd] = MFMA16(ap[i][0], b0, o_acc[i][jd]);
                    o_acc[i][jd] = MFMA16(ap[i][1], b1, o_acc[i][jd]);
                }
            }
        }
    }
#undef PREFETCH

    // l reduction: after xor16+xor32 every lane holds its m16-column's full
    // sum; invert once, then shfl-gather 1/l for the O-store lanes (no LDS).
    float rinv[2];
#pragma unroll
    for (int ni = 0; ni < 2; ni++) {
        float v = lsum[ni];
        v += __shfl_xor(v, 16);
        v += __shfl_xor(v, 32);
        rinv[ni] = 1.0f / v;
    }
    float ri[2][4];
#pragma unroll
    for (int i = 0; i < 2; i++)
#pragma unroll
        for (int r = 0; r < 4; r++)
            ri[i][r] = __shfl(rinv[i], quad * 4 + r);   // lane p holds column p

#pragma unroll
    for (int i = 0; i < 2; i++)
#pragma unroll
        for (int jd = 0; jd < 4; jd++)
#pragma unroll
            for (int r = 0; r < 4; r++) {
                const int row = qrow0 + i * 16 + quad * 4 + r;
                O[(rowbase + row) * 1024 + h * 64 + jd * 16 + m16] =
                    __float2bfloat16(o_acc[i][jd][r] * ri[i][r]);
            }
}

// ---------------------------------------------------------------------------
extern "C" void kernel_launch(void* const* d_in, const int* in_sizes, int n_in,
                              void* d_out, int out_size, void* d_ws, size_t ws_size,
                              hipStream_t stream)
{
    const float* x  = (const float*)d_in[0];
    const float* qw = (const float*)d_in[1];
    const float* kw = (const float*)d_in[2];
    const float* vw = (const float*)d_in[3];
    const float* ow = (const float*)d_in[4];

    const int BS = 8192, D = 1024, S = 2048;
    const size_t MiB = 1024 * 1024;

    char* ws = (char*)d_ws;
    __hip_bfloat16* xb  = (__hip_bfloat16*)(ws);
    __hip_bfloat16* Qb  = (__hip_bfloat16*)(ws + 16 * MiB); // also AO
    __hip_bfloat16* Kb  = (__hip_bfloat16*)(ws + 32 * MiB);
    __hip_bfloat16* Vtb = (__hip_bfloat16*)(ws + 48 * MiB);
    __hip_bfloat16* wqb = (__hip_bfloat16*)(ws + 64 * MiB);
    __hip_bfloat16* wkb = (__hip_bfloat16*)(ws + 66 * MiB);
    __hip_bfloat16* wvb = (__hip_bfloat16*)(ws + 68 * MiB);
    __hip_bfloat16* wob = (__hip_bfloat16*)(ws + 70 * MiB);
    // rope table lives in d_out's tail (512 KB at +31 MiB): written by
    // convert_x_table, read by qkv_gemm, dead before gemm_o overwrites d_out.
    float2* table = (float2*)((char*)d_out + 31 * MiB);
    const bool wbf = ws_size >= 72 * MiB;                   // fast path fits?

    dim3 blk(256);
    convert_x_table<<<4096 + 256, blk, 0, stream>>>(x, xb, table);
    if (wbf) {
        convert4_kernel<<<4 * (D * D) / 2048, blk, 0, stream>>>(
            qw, kw, vw, ow, wqb, wkb, wvb, wob);
        qkv_gemm<1><<<64 * 48, blk, 0, stream>>>(xb, wqb, wkb, wvb, Qb, Kb, Vtb, table);
    } else {
        qkv_gemm<0><<<64 * 48, blk, 0, stream>>>(xb, qw, kw, vw, Qb, Kb, Vtb, table);
    }
    attn_kernel<<<4 * 16 * (S / 128), blk, 0, stream>>>(Qb, Kb, Vtb, Qb /*AO*/, S, BS);
    if (wbf) gemm_o<1><<<(BS / 128) * (D / 64), blk, 0, stream>>>(Qb, wob, (float*)d_out, BS, D, D);
    else     gemm_o<0><<<(BS / 128) * (D / 64), blk, 0, stream>>>(Qb, ow,  (float*)d_out, BS, D, D);
}